// Round 1
// baseline (7466.034 us; speedup 1.0000x reference)
//
#include <hip/hip_runtime.h>
#include <math.h>

#define B 512
#define D 1024
#define H 512
#define C 48
#define K 3
#define T 25
#define DP1 1025        // D+1
#define FEAT 6288       // 2*K*D + K*C
#define G4H 2048        // 4*H
#define BT 8            // batch tile for matmul kernels

__device__ __forceinline__ float sigf(float x){ return 1.0f/(1.0f+expf(-x)); }

// ---------- one-time setup kernels ----------

__global__ void k_transpose(const float* __restrict__ src, float* __restrict__ dst, int rows, int cols){
    int idx = blockIdx.x*256 + threadIdx.x;
    if (idx < rows*cols){ int r = idx/cols, c2 = idx%cols; dst[c2*rows + r] = src[idx]; }
}

__global__ void k_zero(float* p, int n){
    int i = blockIdx.x*256 + threadIdx.x; if (i<n) p[i]=0.f;
}

// per-TAB classifier: Y[k,b,:] = softmax(cat(S,R) @ cls_W[k] + cls_b[k])
__global__ void k_cls(const float* __restrict__ S, const float* __restrict__ R,
                      const float* __restrict__ clsW, const float* __restrict__ clsb,
                      float* __restrict__ Y){
    int kb = blockIdx.x; int k = kb / B; int b = kb % B;
    int t = threadIdx.x; // 64 threads
    __shared__ float sr[64];
    __shared__ float lg[C];
    __shared__ float mred[2];
    float acc = (t<C) ? clsb[k*C+t] : 0.f;
    const float* W = clsW + (size_t)k*2*D*C;
    for (int i0=0; i0<2*D; i0+=64){
        int i = i0 + t;
        sr[t] = (i < D) ? S[((size_t)k*B+b)*D + i] : R[((size_t)k*B+b)*D + (i-D)];
        __syncthreads();
        if (t < C){
            for (int ii=0; ii<64; ++ii) acc += sr[ii]*W[(size_t)(i0+ii)*C + t];
        }
        __syncthreads();
    }
    if (t<C) lg[t]=acc;
    __syncthreads();
    if (t==0){
        float m=lg[0]; for(int c2=1;c2<C;c2++) m=fmaxf(m,lg[c2]);
        float s=0.f; for(int c2=0;c2<C;c2++) s+=expf(lg[c2]-m);
        mred[0]=m; mred[1]=s;
    }
    __syncthreads();
    if (t<C) Y[((size_t)k*B+b)*C + t] = expf(lg[t]-mred[0])/mred[1];
}

__global__ void k_curr_action(const float* __restrict__ Y, float* __restrict__ outca){
    int i = blockIdx.x*256+threadIdx.x; if (i>=B*C) return;
    int b=i/C, c2=i%C;
    outca[i] = Y[((size_t)0*B+b)*C+c2] + Y[((size_t)1*B+b)*C+c2] + Y[((size_t)2*B+b)*C+c2];
}

__device__ __forceinline__ float feat_val(const float* Y, const float* S, const float* R, int b, int i){
    if (i < K*C){ int k=i/C, c2=i%C; return Y[((size_t)k*B+b)*C+c2]; }
    i -= K*C;
    if (i < K*D){ int k=i/D, d=i%D; return S[((size_t)k*B+b)*D+d]; }
    i -= K*D; { int k=i/D, d=i%D; return R[((size_t)k*B+b)*D+d]; }
}

// x0 = feat @ lin_W + lin_b ; feat gathered on the fly. grid (B/BT, 5), block 256
__global__ void k_x0(const float* __restrict__ Y, const float* __restrict__ S, const float* __restrict__ R,
                     const float* __restrict__ linW, const float* __restrict__ linb, float* __restrict__ x){
    int b0 = blockIdx.x*BT;
    int j = blockIdx.y*256 + threadIdx.x;
    __shared__ float fs[BT][32];
    float acc[BT];
    float bias = (j<DP1)? linb[j] : 0.f;
    #pragma unroll
    for (int bb=0;bb<BT;bb++) acc[bb]=bias;
    int tb = threadIdx.x >> 5, ti = threadIdx.x & 31;
    for (int i0=0; i0<FEAT; i0+=32){
        int i = i0 + ti;
        fs[tb][ti] = (i<FEAT)? feat_val(Y,S,R,b0+tb,i) : 0.f;
        __syncthreads();
        int lim = min(32, FEAT-i0);
        if (j < DP1){
            for (int ii=0; ii<lim; ++ii){
                float w = linW[(size_t)(i0+ii)*DP1 + j];
                #pragma unroll
                for (int bb=0;bb<BT;bb++) acc[bb] += fs[bb][ii]*w;
            }
        }
        __syncthreads();
    }
    if (j<DP1){
        #pragma unroll
        for (int bb=0;bb<BT;bb++) x[(size_t)(b0+bb)*DP1 + j] = acc[bb];
    }
}

// curr_dur = Rf @ dur_W + dur_b, one block per b
__global__ void k_dur0(const float* __restrict__ R, const float* __restrict__ durW,
                       const float* __restrict__ durb, float* __restrict__ outpad){
    int b = blockIdx.x; int t = threadIdx.x;
    __shared__ float red[256];
    float p=0.f;
    for (int i=t; i<K*D; i+=256){ int k=i>>10, d=i&1023; p += R[((size_t)k*B+b)*D+d]*durW[i]; }
    red[t]=p; __syncthreads();
    for (int s=128;s>0;s>>=1){ if(t<s) red[t]+=red[t+s]; __syncthreads(); }
    if (t==0) outpad[(size_t)b*(T+1)] = red[0] + durb[0];
}

// ---------- per-step kernels ----------

// gates = x @ W_ih^T + h @ W_hh^T + b_ih + b_hh. grid (B/BT, 8), block 256
__global__ void k_gates(const float* __restrict__ x, const float* __restrict__ h,
                        const float* __restrict__ WihT, const float* __restrict__ WhhT,
                        const float* __restrict__ bih, const float* __restrict__ bhh,
                        float* __restrict__ gates){
    int b0 = blockIdx.x*BT;
    int j = blockIdx.y*256 + threadIdx.x; // < 2048
    __shared__ float fs[BT][32];
    float acc[BT];
    float bias = bih[j]+bhh[j];
    #pragma unroll
    for (int bb=0;bb<BT;bb++) acc[bb]=bias;
    int tb = threadIdx.x >> 5, ti = threadIdx.x & 31;
    for (int i0=0;i0<DP1;i0+=32){
        int i=i0+ti;
        fs[tb][ti] = (i<DP1)? x[(size_t)(b0+tb)*DP1+i] : 0.f;
        __syncthreads();
        int lim = min(32, DP1-i0);
        for (int ii=0; ii<lim; ++ii){
            float w = WihT[(size_t)(i0+ii)*G4H + j];
            #pragma unroll
            for (int bb=0;bb<BT;bb++) acc[bb]+=fs[bb][ii]*w;
        }
        __syncthreads();
    }
    for (int p0=0;p0<H;p0+=32){
        fs[tb][ti] = h[(size_t)(b0+tb)*H + p0+ti];
        __syncthreads();
        for (int ii=0; ii<32; ++ii){
            float w = WhhT[(size_t)(p0+ii)*G4H + j];
            #pragma unroll
            for (int bb=0;bb<BT;bb++) acc[bb]+=fs[bb][ii]*w;
        }
        __syncthreads();
    }
    #pragma unroll
    for (int bb=0;bb<BT;bb++) gates[(size_t)(b0+bb)*G4H + j] = acc[bb];
}

__global__ void k_lstm(const float* __restrict__ gates, float* __restrict__ c, float* __restrict__ hnew){
    int idx = blockIdx.x*256+threadIdx.x; if (idx>=B*H) return;
    int b = idx/H, j = idx%H;
    const float* g = gates + (size_t)b*G4H;
    float ig = sigf(g[j]), fg = sigf(g[H+j]), gg = tanhf(g[2*H+j]), og = sigf(g[3*H+j]);
    float cn = fg*c[idx] + ig*gg;
    c[idx] = cn;
    hnew[idx] = og*tanhf(cn);
}

// logits/probs/labels: one block (64 thr) per b
__global__ void k_logits(const float* __restrict__ h, const float* __restrict__ Wp, const float* __restrict__ bp,
                         float* __restrict__ outlab, float* __restrict__ outprobs,
                         int* __restrict__ labs, int tstep){
    int b = blockIdx.x; int t = threadIdx.x; // 64
    __shared__ float hs[64];
    __shared__ float lg[C];
    __shared__ float mred[2];
    float acc = (t<C)? bp[t] : 0.f;
    for (int p0=0;p0<H;p0+=64){
        hs[t] = h[(size_t)b*H + p0 + t];
        __syncthreads();
        if (t<C){ for (int ii=0; ii<64; ++ii) acc += hs[ii]*Wp[(size_t)(p0+ii)*C + t]; }
        __syncthreads();
    }
    if (t<C) lg[t]=acc;
    __syncthreads();
    if (t==0){
        float m=lg[0]; int best=0;
        for (int c2=1;c2<C;c2++){ if (lg[c2]>m){ m=lg[c2]; best=c2; } }
        float s=0.f; for (int c2=0;c2<C;c2++) s+=expf(lg[c2]-m);
        mred[0]=m; mred[1]=s;
        outlab[(size_t)tstep*B + b] = (float)best;
        labs[b]=best;
    }
    __syncthreads();
    if (t<C) outprobs[(size_t)b*(T*C) + tstep*C + t] = expf(lg[t]-mred[0])/mred[1];
}

// q = (h @ Wattn) / 32. grid (B/BT, 4), block 256
__global__ void k_q(const float* __restrict__ h, const float* __restrict__ Wattn, float* __restrict__ q){
    int b0 = blockIdx.x*BT;
    int j = blockIdx.y*256 + threadIdx.x; // < 1024
    __shared__ float fs[BT][32];
    float acc[BT];
    #pragma unroll
    for (int bb=0;bb<BT;bb++) acc[bb]=0.f;
    int tb=threadIdx.x>>5, ti=threadIdx.x&31;
    for (int p0=0;p0<H;p0+=32){
        fs[tb][ti] = h[(size_t)(b0+tb)*H + p0+ti];
        __syncthreads();
        for (int ii=0;ii<32;++ii){
            float w = Wattn[(size_t)(p0+ii)*D + j];
            #pragma unroll
            for (int bb=0;bb<BT;bb++) acc[bb]+=fs[bb][ii]*w;
        }
        __syncthreads();
    }
    #pragma unroll
    for (int bb=0;bb<BT;bb++) q[(size_t)(b0+bb)*D + j] = acc[bb]*0.03125f;
}

// attention over K=3 + dur head; one block (256 thr) per b
__global__ void k_attn_dur(const float* __restrict__ q, const float* __restrict__ S,
                           const float* __restrict__ hprev,
                           const float* __restrict__ Wdur, const float* __restrict__ bdur,
                           float* __restrict__ outatt, float* __restrict__ outpad,
                           float* __restrict__ wsdur, int tstep){
    int b = blockIdx.x; int t = threadIdx.x; // 256
    __shared__ float red[256];
    __shared__ float aw[K];
    float sk[K];
    for (int k=0;k<K;k++){
        float p=0.f;
        const float* Sk = S + ((size_t)k*B+b)*D;
        for (int d=t; d<D; d+=256) p += q[(size_t)b*D+d]*Sk[d];
        red[t]=p; __syncthreads();
        for (int s=128;s>0;s>>=1){ if(t<s) red[t]+=red[t+s]; __syncthreads(); }
        sk[k]=red[0];
        __syncthreads();
    }
    if (t==0){
        float m = fmaxf(sk[0], fmaxf(sk[1], sk[2]));
        float e0=expf(sk[0]-m), e1=expf(sk[1]-m), e2=expf(sk[2]-m);
        float s=e0+e1+e2;
        aw[0]=e0/s; aw[1]=e1/s; aw[2]=e2/s;
    }
    __syncthreads();
    float a0=aw[0], a1=aw[1], a2=aw[2];
    float dp=0.f;
    const float* S0 = S + ((size_t)0*B+b)*D;
    const float* S1 = S + ((size_t)1*B+b)*D;
    const float* S2 = S + ((size_t)2*B+b)*D;
    for (int d=t; d<D; d+=256){
        float av = a0*S0[d] + a1*S1[d] + a2*S2[d];
        outatt[(size_t)tstep*B*D + (size_t)b*D + d] = av;
        dp += av * Wdur[d];
    }
    for (int p=t; p<H; p+=256) dp += hprev[(size_t)b*H+p]*Wdur[D+p];
    red[t]=dp; __syncthreads();
    for (int s=128;s>0;s>>=1){ if(t<s) red[t]+=red[t+s]; __syncthreads(); }
    if (t==0){ float dv = red[0]+bdur[0]; outpad[(size_t)b*(T+1)+tstep+1] = dv; wsdur[b]=dv; }
}

// next x = [embed[label], dur]
__global__ void k_nx(const int* __restrict__ labs, const float* __restrict__ wsdur,
                     const float* __restrict__ embed, float* __restrict__ x){
    int idx = blockIdx.x*256+threadIdx.x; if (idx>=B*DP1) return;
    int b = idx/DP1, j = idx%DP1;
    x[idx] = (j<D)? embed[(size_t)labs[b]*D + j] : wsdur[b];
}

// ---------- host ----------

extern "C" void kernel_launch(void* const* d_in, const int* in_sizes, int n_in,
                              void* d_out, int out_size, void* d_ws, size_t ws_size,
                              hipStream_t stream) {
    const float* S    = (const float*)d_in[0];
    const float* R    = (const float*)d_in[1];
    const float* clsW = (const float*)d_in[2];
    const float* clsb = (const float*)d_in[3];
    const float* durW = (const float*)d_in[4];
    const float* durb = (const float*)d_in[5];
    const float* linW = (const float*)d_in[6];
    const float* linb = (const float*)d_in[7];
    const float* Wih  = (const float*)d_in[8];
    const float* Whh  = (const float*)d_in[9];
    const float* bih  = (const float*)d_in[10];
    const float* bhh  = (const float*)d_in[11];
    const float* Wp   = (const float*)d_in[12];
    const float* bp   = (const float*)d_in[13];
    const float* Wdur = (const float*)d_in[14];
    const float* bdur = (const float*)d_in[15];
    const float* embed= (const float*)d_in[16];
    const float* Wattn= (const float*)d_in[17];

    float* out = (float*)d_out;
    // output layout: labels[T,B] | probs[B,T,C] | curr_action[B,C] | pad[B,T+1] | att[T,B,D]
    float* outlab   = out;                 // 12800
    float* outprobs = out + 12800;         // 614400
    float* outca    = out + 627200;        // 24576
    float* outpad   = out + 651776;        // 13312
    float* outatt   = out + 665088;        // 13107200

    float* ws = (float*)d_ws;
    float* WihT  = ws;                     // 1025*2048 = 2099200
    float* WhhT  = WihT + 2099200;         // 512*2048  = 1048576
    float* Y     = WhhT + 1048576;         // 3*512*48  = 73728
    float* x     = Y + 73728;              // 512*1025  = 524800
    float* hA    = x + 524800;             // 262144
    float* hB    = hA + 262144;            // 262144
    float* c     = hB + 262144;            // 262144
    float* gates = c + 262144;             // 512*2048  = 1048576
    float* q     = gates + 1048576;        // 512*1024  = 524288
    float* wsdur = q + 524288;             // 512
    int*   labs  = (int*)(wsdur + 512);    // 512

    k_transpose<<<(2048*1025+255)/256,256,0,stream>>>(Wih, WihT, 2048, 1025);
    k_transpose<<<(2048*512+255)/256,256,0,stream>>>(Whh, WhhT, 2048, 512);
    k_zero<<<(262144*3+255)/256,256,0,stream>>>(hA, 262144*3); // hA,hB,c contiguous
    k_cls<<<K*B,64,0,stream>>>(S,R,clsW,clsb,Y);
    k_curr_action<<<96,256,0,stream>>>(Y,outca);
    k_x0<<<dim3(64,5),256,0,stream>>>(Y,S,R,linW,linb,x);
    k_dur0<<<B,256,0,stream>>>(R,durW,durb,outpad);

    for (int t=0;t<T;t++){
        k_gates<<<dim3(64,8),256,0,stream>>>(x,hA,WihT,WhhT,bih,bhh,gates);
        k_lstm<<<(B*H+255)/256,256,0,stream>>>(gates,c,hB);
        k_logits<<<B,64,0,stream>>>(hB,Wp,bp,outlab,outprobs,labs,t);
        k_q<<<dim3(64,4),256,0,stream>>>(hB,Wattn,q);
        k_attn_dur<<<B,256,0,stream>>>(q,S,hA,Wdur,bdur,outatt,outpad,wsdur,t);
        k_nx<<<(B*DP1+255)/256,256,0,stream>>>(labs,wsdur,embed,x);
        float* tmp=hA; hA=hB; hB=tmp;
    }
}

// Round 2
// 3456.002 us; speedup vs baseline: 2.1603x; 2.1603x over previous
//
#include <hip/hip_runtime.h>
#include <math.h>

#define B 512
#define D 1024
#define H 512
#define C 48
#define K 3
#define T 25
#define DP1 1025        // D+1
#define FEAT 6288       // 2*K*D + K*C
#define G4H 2048        // 4*H
#define NZ 1072         // C + D  (logits | q)

__device__ __forceinline__ float sigf(float x){ return 1.0f/(1.0f+expf(-x)); }

__device__ __forceinline__ float feat_val(const float* __restrict__ Y, const float* __restrict__ S,
                                          const float* __restrict__ R, int b, int i){
    if (i < K*C){ int k=i/C, c2=i%C; return Y[((size_t)k*B+b)*C+c2]; }
    i -= K*C;
    if (i < K*D){ int k=i>>10, d=i&1023; return S[((size_t)k*B+b)*D+d]; }
    i -= K*D; { int k=i>>10, d=i&1023; return R[((size_t)k*B+b)*D+d]; }
}

// ---------- generic 64x64-tile fp32 GEMM, BK=16, register-prefetch pipeline ----------
// C[M,N] = A[M,K] @ B[K,N]  + epilogue
// epi 0: += bias[col] (bias may be null)
// epi 1: += gx0[r*2048+col]                         (gates, step 0)
// epi 2: += E[labs[r]*2048+col] + dur[r]*wl[col]    (gates, steps>=1)
// gatherA: A element (m,k) = feat_val(Y,S,R,m,k)    (x0 GEMM)
__global__ __launch_bounds__(256)
void k_gemm(const float* __restrict__ A, const float* __restrict__ Bm, float* __restrict__ Cc,
            int M, int N, int K_, int lda, int ldb, int ldc,
            const float* __restrict__ bias, int epi, int gatherA,
            const float* __restrict__ E, const float* __restrict__ wl,
            const float* __restrict__ gx0, const int* __restrict__ labs,
            const float* __restrict__ dur,
            const float* __restrict__ Y, const float* __restrict__ S, const float* __restrict__ R)
{
    __shared__ __align__(16) float As[16][68];   // k-major, padded: 16B-aligned rows, conflict-free
    __shared__ __align__(16) float Bs[16][64];
    int t = threadIdx.x;
    int m0 = blockIdx.x*64, n0 = blockIdx.y*64;
    int aM[4], aK[4], bK[4], bN[4];
    #pragma unroll
    for (int i=0;i<4;i++){ int e=t+256*i; aM[i]=e>>4; aK[i]=e&15; bK[i]=e>>6; bN[i]=e&63; }
    float ra[4], rb[4];
    #pragma unroll
    for (int i=0;i<4;i++){
        int m=m0+aM[i], k=aK[i];
        ra[i] = (m<M && k<K_) ? (gatherA ? feat_val(Y,S,R,m,k) : A[(size_t)m*lda+k]) : 0.f;
        int kb=bK[i], n=n0+bN[i];
        rb[i] = (kb<K_ && n<N) ? Bm[(size_t)kb*ldb+n] : 0.f;
    }
    float acc[4][4] = {};
    int r0=(t>>4)*4, c0=(t&15)*4;
    int k0=0;
    while (true){
        #pragma unroll
        for (int i=0;i<4;i++){ As[aK[i]][aM[i]]=ra[i]; Bs[bK[i]][bN[i]]=rb[i]; }
        __syncthreads();
        int kn=k0+16;
        if (kn<K_){
            #pragma unroll
            for (int i=0;i<4;i++){
                int m=m0+aM[i], k=kn+aK[i];
                ra[i] = (m<M && k<K_) ? (gatherA ? feat_val(Y,S,R,m,k) : A[(size_t)m*lda+k]) : 0.f;
                int kb=kn+bK[i], n=n0+bN[i];
                rb[i] = (kb<K_ && n<N) ? Bm[(size_t)kb*ldb+n] : 0.f;
            }
        }
        #pragma unroll
        for (int kk=0;kk<16;kk++){
            float4 av=*(const float4*)&As[kk][r0];
            float4 bv=*(const float4*)&Bs[kk][c0];
            acc[0][0]+=av.x*bv.x; acc[0][1]+=av.x*bv.y; acc[0][2]+=av.x*bv.z; acc[0][3]+=av.x*bv.w;
            acc[1][0]+=av.y*bv.x; acc[1][1]+=av.y*bv.y; acc[1][2]+=av.y*bv.z; acc[1][3]+=av.y*bv.w;
            acc[2][0]+=av.z*bv.x; acc[2][1]+=av.z*bv.y; acc[2][2]+=av.z*bv.z; acc[2][3]+=av.z*bv.w;
            acc[3][0]+=av.w*bv.x; acc[3][1]+=av.w*bv.y; acc[3][2]+=av.w*bv.z; acc[3][3]+=av.w*bv.w;
        }
        k0=kn;
        if (k0>=K_) break;
        __syncthreads();
    }
    #pragma unroll
    for (int i=0;i<4;i++){
        int r=m0+r0+i;
        if (r>=M) continue;
        size_t rbase=(size_t)r*ldc;
        if (epi==0){
            #pragma unroll
            for (int j=0;j<4;j++){
                int cg=n0+c0+j;
                if (cg<N) Cc[rbase+cg] = acc[i][j] + (bias? bias[cg] : 0.f);
            }
        } else if (epi==1){
            #pragma unroll
            for (int j=0;j<4;j++){
                int cg=n0+c0+j;
                Cc[rbase+cg] = acc[i][j] + gx0[(size_t)r*G4H+cg];
            }
        } else {
            int lb=labs[r]; float dv=dur[r];
            #pragma unroll
            for (int j=0;j<4;j++){
                int cg=n0+c0+j;
                Cc[rbase+cg] = acc[i][j] + E[(size_t)lb*G4H+cg] + dv*wl[cg];
            }
        }
    }
}

// ---------- setup kernels ----------

__global__ void k_transpose(const float* __restrict__ src, float* __restrict__ dst, int rows, int cols){
    int idx = blockIdx.x*256 + threadIdx.x;
    if (idx < rows*cols){ int r = idx/cols, c2 = idx%cols; dst[(size_t)c2*rows + r] = src[idx]; }
}

__global__ void k_zero(float* p, int n){
    int i = blockIdx.x*256 + threadIdx.x; if (i<n) p[i]=0.f;
}

// bias2 = b_ih + b_hh ; wl = W_ih[:,1024] ; Wcat = [Wp | Wattn/32] ; biascat = [bp | 0]
__global__ void k_prep(const float* __restrict__ bih, const float* __restrict__ bhh,
                       const float* __restrict__ Wih, const float* __restrict__ Wp,
                       const float* __restrict__ bp, const float* __restrict__ Wattn,
                       float* __restrict__ bias2, float* __restrict__ wl,
                       float* __restrict__ Wcat, float* __restrict__ biascat){
    int i = blockIdx.x*256 + threadIdx.x;
    if (i < G4H){ bias2[i]=bih[i]+bhh[i]; wl[i]=Wih[(size_t)i*DP1 + 1024]; }
    if (i < NZ) biascat[i] = (i<C)? bp[i] : 0.f;
    if (i < H*NZ){
        int k=i/NZ, col=i%NZ;
        Wcat[i] = (col<C)? Wp[k*C+col] : Wattn[(size_t)k*D + (col-C)]*0.03125f;
    }
}

// per-TAB classifier softmax
__global__ void k_cls(const float* __restrict__ S, const float* __restrict__ R,
                      const float* __restrict__ clsW, const float* __restrict__ clsb,
                      float* __restrict__ Y){
    int kb = blockIdx.x; int k = kb / B; int b = kb % B;
    int t = threadIdx.x; // 64
    __shared__ float sr[64];
    __shared__ float lg[C];
    __shared__ float mred[2];
    float acc = (t<C) ? clsb[k*C+t] : 0.f;
    const float* W = clsW + (size_t)k*2*D*C;
    for (int i0=0; i0<2*D; i0+=64){
        int i = i0 + t;
        sr[t] = (i < D) ? S[((size_t)k*B+b)*D + i] : R[((size_t)k*B+b)*D + (i-D)];
        __syncthreads();
        if (t < C){ for (int ii=0; ii<64; ++ii) acc += sr[ii]*W[(size_t)(i0+ii)*C + t]; }
        __syncthreads();
    }
    if (t<C) lg[t]=acc;
    __syncthreads();
    if (t==0){
        float m=lg[0]; for(int c2=1;c2<C;c2++) m=fmaxf(m,lg[c2]);
        float s=0.f; for(int c2=0;c2<C;c2++) s+=expf(lg[c2]-m);
        mred[0]=m; mred[1]=s;
    }
    __syncthreads();
    if (t<C) Y[((size_t)k*B+b)*C + t] = expf(lg[t]-mred[0])/mred[1];
}

__global__ void k_curr_action(const float* __restrict__ Y, float* __restrict__ outca){
    int i = blockIdx.x*256+threadIdx.x; if (i>=B*C) return;
    int b=i/C, c2=i%C;
    outca[i] = Y[((size_t)0*B+b)*C+c2] + Y[((size_t)1*B+b)*C+c2] + Y[((size_t)2*B+b)*C+c2];
}

__global__ void k_dur0(const float* __restrict__ R, const float* __restrict__ durW,
                       const float* __restrict__ durb, float* __restrict__ outpad){
    int b = blockIdx.x; int t = threadIdx.x;
    __shared__ float red[256];
    float p=0.f;
    for (int i=t; i<K*D; i+=256){ int k=i>>10, d=i&1023; p += R[((size_t)k*B+b)*D+d]*durW[i]; }
    red[t]=p; __syncthreads();
    for (int s=128;s>0;s>>=1){ if(t<s) red[t]+=red[t+s]; __syncthreads(); }
    if (t==0) outpad[(size_t)b*(T+1)] = red[0] + durb[0];
}

// ---------- per-step kernels ----------

__global__ void k_lstm(const float* __restrict__ gates, float* __restrict__ c, float* __restrict__ hnew){
    int idx = blockIdx.x*256+threadIdx.x; if (idx>=B*H) return;
    int b = idx/H, j = idx%H;
    const float* g = gates + (size_t)b*G4H;
    float ig = sigf(g[j]), fg = sigf(g[H+j]), gg = tanhf(g[2*H+j]), og = sigf(g[3*H+j]);
    float cn = fg*c[idx] + ig*gg;
    c[idx] = cn;
    hnew[idx] = og*tanhf(cn);
}

// fused: logits softmax/argmax + attention + dur head (one block of 256 per b)
__global__ void k_post(const float* __restrict__ Z, const float* __restrict__ S,
                       const float* __restrict__ hold,
                       const float* __restrict__ Wdur, const float* __restrict__ bdur,
                       float* __restrict__ outlab, float* __restrict__ outprobs,
                       float* __restrict__ outatt, float* __restrict__ outpad,
                       int* __restrict__ labs, float* __restrict__ wsdur, int tstep)
{
    int b=blockIdx.x, t=threadIdx.x;
    __shared__ float red[256];
    __shared__ float lg[C];
    __shared__ float sm2[2];
    __shared__ float aw[3];
    const float* zb = Z + (size_t)b*NZ;
    if (t<C) lg[t]=zb[t];
    __syncthreads();
    if (t==0){
        float m=lg[0]; int best=0;
        for (int c2=1;c2<C;c2++) if (lg[c2]>m){m=lg[c2];best=c2;}
        float s=0.f; for (int c2=0;c2<C;c2++) s+=expf(lg[c2]-m);
        sm2[0]=m; sm2[1]=s; labs[b]=best;
        outlab[(size_t)tstep*B+b]=(float)best;
    }
    __syncthreads();
    if (t<C) outprobs[(size_t)b*(T*C)+tstep*C+t]=expf(lg[t]-sm2[0])/sm2[1];
    const float* q  = zb + C;             // already scaled by 1/32 via Wcat
    const float* S0 = S + (size_t)b*D;
    const float* S1 = S0 + (size_t)B*D;
    const float* S2 = S1 + (size_t)B*D;
    float pv[3]={0.f,0.f,0.f};
    for (int d=t; d<D; d+=256){ float qd=q[d]; pv[0]+=qd*S0[d]; pv[1]+=qd*S1[d]; pv[2]+=qd*S2[d]; }
    for (int k=0;k<3;k++){
        red[t]=pv[k]; __syncthreads();
        for (int s=128;s>0;s>>=1){ if (t<s) red[t]+=red[t+s]; __syncthreads(); }
        if (t==0) aw[k]=red[0];
        __syncthreads();
    }
    if (t==0){
        float m=fmaxf(aw[0],fmaxf(aw[1],aw[2]));
        float e0=expf(aw[0]-m), e1=expf(aw[1]-m), e2=expf(aw[2]-m);
        float s=e0+e1+e2;
        aw[0]=e0/s; aw[1]=e1/s; aw[2]=e2/s;
    }
    __syncthreads();
    float a0=aw[0],a1=aw[1],a2=aw[2];
    float dp=0.f;
    for (int d=t; d<D; d+=256){
        float av=a0*S0[d]+a1*S1[d]+a2*S2[d];
        outatt[(size_t)tstep*B*D + (size_t)b*D + d]=av;
        dp+=av*Wdur[d];
    }
    for (int p=t;p<H;p+=256) dp += hold[(size_t)b*H+p]*Wdur[D+p];
    red[t]=dp; __syncthreads();
    for (int s=128;s>0;s>>=1){ if (t<s) red[t]+=red[t+s]; __syncthreads(); }
    if (t==0){ float dv=red[0]+bdur[0]; outpad[(size_t)b*(T+1)+tstep+1]=dv; wsdur[b]=dv; }
}

// ---------- host ----------

extern "C" void kernel_launch(void* const* d_in, const int* in_sizes, int n_in,
                              void* d_out, int out_size, void* d_ws, size_t ws_size,
                              hipStream_t stream) {
    const float* S    = (const float*)d_in[0];
    const float* R    = (const float*)d_in[1];
    const float* clsW = (const float*)d_in[2];
    const float* clsb = (const float*)d_in[3];
    const float* durW = (const float*)d_in[4];
    const float* durb = (const float*)d_in[5];
    const float* linW = (const float*)d_in[6];
    const float* linb = (const float*)d_in[7];
    const float* Wih  = (const float*)d_in[8];
    const float* Whh  = (const float*)d_in[9];
    const float* bih  = (const float*)d_in[10];
    const float* bhh  = (const float*)d_in[11];
    const float* Wp   = (const float*)d_in[12];
    const float* bp   = (const float*)d_in[13];
    const float* Wdur = (const float*)d_in[14];
    const float* bdur = (const float*)d_in[15];
    const float* embed= (const float*)d_in[16];
    const float* Wattn= (const float*)d_in[17];

    float* out = (float*)d_out;
    float* outlab   = out;                 // [T,B] 12800
    float* outprobs = out + 12800;         // [B,T,C] 614400
    float* outca    = out + 627200;        // [B,C] 24576
    float* outpad   = out + 651776;        // [B,T+1] 13312
    float* outatt   = out + 665088;        // [T,B,D] 13107200

    float* ws = (float*)d_ws;
    // persistent layout (floats). WihT region [0,2099200) is setup-only and is
    // aliased by gates[0,1048576)+Z[1048576,1597440) during the step loop; the
    // wl row lives in wl_safe so nothing in steps touches the aliased region.
    float* WihT   = ws + 0;                // 1025*2048 (setup only)
    float* WhhT   = ws + 2099200;          // 512*2048
    float* E      = ws + 3147776;          // 48*2048
    float* bias2  = ws + 3246080;          // 2048
    float* Wcat   = ws + 3248128;          // 512*1072
    float* biascat= ws + 3796992;          // 1088
    float* Y      = ws + 3798080;          // 3*512*48
    float* gx0    = ws + 3871808;          // 512*2048
    float* hA     = ws + 4920384;          // 262144
    float* hB     = ws + 5182528;          // 262144
    float* c      = ws + 5444672;          // 262144
    float* wsdur  = ws + 5706816;          // 512
    int*   labs   = (int*)(ws + 5707328);  // 512
    float* wl     = ws + 5707840;          // 2048
    // step-scratch aliases (over WihT region):
    float* gates  = ws + 0;                // 512*2048
    float* Z      = ws + 1048576;          // 512*1072
    // setup-scratch alias (over hA/hB/c, zeroed afterwards):
    float* x0     = hA;                    // 512*1025 = 524800 < 786432

    // ---- setup ----
    k_transpose<<<(2048*1025+255)/256,256,0,stream>>>(Wih, WihT, 2048, 1025);
    k_transpose<<<(2048*512+255)/256,256,0,stream>>>(Whh, WhhT, 2048, 512);
    k_prep<<<(H*NZ+255)/256,256,0,stream>>>(bih,bhh,Wih,Wp,bp,Wattn,bias2,wl,Wcat,biascat);
    k_cls<<<K*B,64,0,stream>>>(S,R,clsW,clsb,Y);
    k_curr_action<<<(B*C+255)/256,256,0,stream>>>(Y,outca);
    // x0 = feat @ lin_W + lin_b   (A gathered on the fly)
    k_gemm<<<dim3(8,17),256,0,stream>>>(nullptr, linW, x0, B, DP1, FEAT, 0, DP1, DP1,
                                        linb, 0, 1, nullptr,nullptr,nullptr,nullptr,nullptr, Y,S,R);
    // gx0 = x0 @ WihT + bias2
    k_gemm<<<dim3(8,32),256,0,stream>>>(x0, WihT, gx0, B, G4H, DP1, DP1, G4H, G4H,
                                        bias2, 0, 0, nullptr,nullptr,nullptr,nullptr,nullptr, nullptr,nullptr,nullptr);
    // E = embed @ WihT[0:1024,:] + bias2
    k_gemm<<<dim3(1,32),256,0,stream>>>(embed, WihT, E, C, G4H, D, D, G4H, G4H,
                                        bias2, 0, 0, nullptr,nullptr,nullptr,nullptr,nullptr, nullptr,nullptr,nullptr);
    k_zero<<<(262144*3+255)/256,256,0,stream>>>(hA, 262144*3);   // hA,hB,c contiguous
    k_dur0<<<B,256,0,stream>>>(R,durW,durb,outpad);

    // ---- scan ----
    float* hOld=hA; float* hNew=hB;
    for (int t=0;t<T;t++){
        int epi = (t==0)? 1 : 2;
        k_gemm<<<dim3(8,32),256,0,stream>>>(hOld, WhhT, gates, B, G4H, H, H, G4H, G4H,
                                            nullptr, epi, 0, E, wl, gx0, labs, wsdur,
                                            nullptr,nullptr,nullptr);
        k_lstm<<<(B*H+255)/256,256,0,stream>>>(gates,c,hNew);
        k_gemm<<<dim3(8,17),256,0,stream>>>(hNew, Wcat, Z, B, NZ, H, H, NZ, NZ,
                                            biascat, 0, 0, nullptr,nullptr,nullptr,nullptr,nullptr,
                                            nullptr,nullptr,nullptr);
        k_post<<<B,256,0,stream>>>(Z,S,hOld,Wdur,bdur,outlab,outprobs,outatt,outpad,labs,wsdur,t);
        float* tmp=hOld; hOld=hNew; hNew=tmp;
    }
}

// Round 3
// 1905.353 us; speedup vs baseline: 3.9185x; 1.8138x over previous
//
#include <hip/hip_runtime.h>
#include <math.h>

#define B 512
#define D 1024
#define H 512
#define C 48
#define K 3
#define T 25
#define DP1 1025
#define FEAT 6288
#define FEATP 6304      // padded feat ld (%4==0)
#define G4H 2048
#define NZ 1072         // C + D

__device__ __forceinline__ float sigf(float x){ return 1.0f/(1.0f+expf(-x)); }

// ---------------- GEMM core: 32x64 tile, BK=32, 256 threads ----------------

__device__ __forceinline__ void load_frag(
    const float* __restrict__ A, const float* __restrict__ Bm,
    int M, int N, int kcnt, int lda, int ldb,
    int m0, int n0, int koff, int avec, int bvec, int t,
    float4& ra, float4& rb0, float4& rb1)
{
    int am = t>>3, ak = (t&7)*4;
    int m = m0 + am;
    int kA = koff + ak;
    if (m < M && avec && (kA+3) < kcnt){
        ra = *(const float4*)&A[(size_t)m*lda + kA];
    } else {
        float* rp = (float*)&ra;
        #pragma unroll
        for (int i=0;i<4;i++) rp[i] = (m<M && (kA+i)<kcnt) ? A[(size_t)m*lda + kA + i] : 0.f;
    }
    int bk = (t>>4)*2, bn = (t&15)*4;
    int n = n0 + bn;
    #pragma unroll
    for (int rr=0; rr<2; ++rr){
        float4& rb = rr ? rb1 : rb0;
        int kB = koff + bk + rr;
        if (kB < kcnt && bvec && (n+3) < N){
            rb = *(const float4*)&Bm[(size_t)kB*ldb + n];
        } else {
            float* rp = (float*)&rb;
            #pragma unroll
            for (int i=0;i<4;i++) rp[i] = (kB<kcnt && (n+i)<N) ? Bm[(size_t)kB*ldb + n + i] : 0.f;
        }
    }
}

__device__ __forceinline__ void gemm_core(
    const float* __restrict__ A, const float* __restrict__ Bm,
    int M, int N, int kcnt, int lda, int ldb,
    int m0, int n0, int avec, int bvec, int t,
    float (* __restrict__ As)[34], float (* __restrict__ Bs)[64],
    float acc[2][4])
{
    float4 ra, rb0, rb1;
    load_frag(A,Bm,M,N,kcnt,lda,ldb,m0,n0,0,avec,bvec,t,ra,rb0,rb1);
    int nIter = (kcnt + 31) >> 5;
    int am = t>>3, ak=(t&7)*4, bk=(t>>4)*2, bn=(t&15)*4;
    int r0 = (t>>4)*2, c0 = (t&15)*4;
    for (int it=0; it<nIter; ++it){
        const float* rp = (const float*)&ra;
        #pragma unroll
        for (int i=0;i<4;i++) As[ak+i][am] = rp[i];
        *(float4*)&Bs[bk][bn]   = rb0;
        *(float4*)&Bs[bk+1][bn] = rb1;
        __syncthreads();
        if (it+1 < nIter)
            load_frag(A,Bm,M,N,kcnt,lda,ldb,m0,n0,(it+1)<<5,avec,bvec,t,ra,rb0,rb1);
        #pragma unroll
        for (int kk=0;kk<32;++kk){
            float2 av = *(const float2*)&As[kk][r0];
            float4 bv = *(const float4*)&Bs[kk][c0];
            acc[0][0] += av.x*bv.x; acc[0][1] += av.x*bv.y;
            acc[0][2] += av.x*bv.z; acc[0][3] += av.x*bv.w;
            acc[1][0] += av.y*bv.x; acc[1][1] += av.y*bv.y;
            acc[1][2] += av.y*bv.z; acc[1][3] += av.y*bv.w;
        }
        __syncthreads();
    }
}

__global__ __launch_bounds__(256)
void k_gemm2(const float* __restrict__ A, const float* __restrict__ Bm, float* __restrict__ Cc,
             int M, int N, int Ktot, int lda, int ldb, int ldc,
             int ksl, size_t cstride, int avec, int bvec)
{
    __shared__ __align__(16) float As[32][34];
    __shared__ __align__(16) float Bs[32][64];
    int t = threadIdx.x;
    int m0 = blockIdx.x*32, n0 = blockIdx.y*64;
    int z = blockIdx.z;
    int kbase = z*ksl;
    int kcnt = (z == (int)gridDim.z-1) ? (Ktot - kbase) : ksl;
    const float* Az = A + kbase;
    const float* Bz = Bm + (size_t)kbase*ldb;
    float acc[2][4] = {};
    gemm_core(Az,Bz,M,N,kcnt,lda,ldb,m0,n0,avec,bvec,t,As,Bs,acc);
    float* Cz = Cc + (size_t)z*cstride;
    int r0=(t>>4)*2, c0=(t&15)*4;
    #pragma unroll
    for (int i=0;i<2;i++){
        int r = m0+r0+i;
        if (r>=M) continue;
        #pragma unroll
        for (int j=0;j<4;j++){
            int n = n0+c0+j;
            if (n < ldc) Cz[(size_t)r*ldc + n] = acc[i][j];
        }
    }
}

// gates GEMM (gate-interleaved cols p=j*4+g) fused with LSTM cell. grid (16,32).
__global__ __launch_bounds__(256)
void k_gates_lstm(const float* __restrict__ h, const float* __restrict__ Whp,
                  const float* __restrict__ E, const float* __restrict__ wl,
                  const int* __restrict__ labs, const float* __restrict__ dur,
                  float* __restrict__ c, float* __restrict__ hNew)
{
    __shared__ __align__(16) float As[32][34];
    __shared__ __align__(16) float Bs[32][64];
    int t=threadIdx.x;
    int m0=blockIdx.x*32, n0=blockIdx.y*64;
    float acc[2][4]={};
    gemm_core(h,Whp,B,G4H,H,H,G4H,m0,n0,1,1,t,As,Bs,acc);
    int r0=(t>>4)*2, c0=(t&15)*4;
    int p = n0+c0;
    int j = p>>2;
    #pragma unroll
    for (int i=0;i<2;i++){
        int r=m0+r0+i;
        int lb = labs[r]; float dv = dur[r];
        const float* ep = &E[(size_t)lb*G4H + p];
        float g0=acc[i][0]+ep[0]+dv*wl[p+0];
        float g1=acc[i][1]+ep[1]+dv*wl[p+1];
        float g2=acc[i][2]+ep[2]+dv*wl[p+2];
        float g3=acc[i][3]+ep[3]+dv*wl[p+3];
        float ig=sigf(g0), fg=sigf(g1), gt=tanhf(g2), og=sigf(g3);
        size_t ci=(size_t)r*H + j;
        float cn = fg*c[ci] + ig*gt;
        c[ci]=cn;
        hNew[ci]=og*tanhf(cn);
    }
}

// t=0: h0=0,c0=0 -> gates = gx0_perm (4 gates contiguous per j)
__global__ void k_lstm0(const float* __restrict__ gx0, float* __restrict__ c, float* __restrict__ h){
    int idx = blockIdx.x*256+threadIdx.x; if (idx>=B*H) return;
    int r=idx>>9, j=idx&511;
    float4 g = *(const float4*)&gx0[(size_t)r*G4H + (j<<2)];
    float cn = sigf(g.x)*tanhf(g.z);
    c[idx]=cn; h[idx]=sigf(g.w)*tanhf(cn);
}

// ---------------- setup kernels ----------------

__global__ void k_trans_perm(const float* __restrict__ src, float* __restrict__ dst, int cols){
    int idx = blockIdx.x*256+threadIdx.x;
    if (idx >= G4H*cols) return;
    int gi = idx / cols, k2 = idx % cols;
    int g = gi >> 9, j = gi & 511;
    dst[(size_t)k2*G4H + ((j<<2) | g)] = src[idx];
}

__global__ void k_prep(const float* __restrict__ bih, const float* __restrict__ bhh,
                       const float* __restrict__ Wp, const float* __restrict__ bp,
                       const float* __restrict__ Wattn,
                       float* __restrict__ bias2p, float* __restrict__ Wcat,
                       float* __restrict__ biascat){
    int i = blockIdx.x*256 + threadIdx.x;
    if (i < G4H){ int g=i&3, j=i>>2; int gi=g*512+j; bias2p[i]=bih[gi]+bhh[gi]; }
    if (i < NZ) biascat[i] = (i<C)? bp[i] : 0.f;
    if (i < H*NZ){
        int k2=i/NZ, col=i%NZ;
        Wcat[i] = (col<C)? Wp[k2*C+col] : Wattn[(size_t)k2*D + (col-C)]*0.03125f;
    }
}

__global__ void k_cls(const float* __restrict__ S, const float* __restrict__ R,
                      const float* __restrict__ clsW, const float* __restrict__ clsb,
                      float* __restrict__ Y){
    int kb = blockIdx.x; int k = kb / B; int b = kb % B;
    int t = threadIdx.x; // 64
    __shared__ float sr[64];
    __shared__ float lg[C];
    __shared__ float mred[2];
    float acc = (t<C) ? clsb[k*C+t] : 0.f;
    const float* W = clsW + (size_t)k*2*D*C;
    for (int i0=0; i0<2*D; i0+=64){
        int i = i0 + t;
        sr[t] = (i < D) ? S[((size_t)k*B+b)*D + i] : R[((size_t)k*B+b)*D + (i-D)];
        __syncthreads();
        if (t < C){ for (int ii=0; ii<64; ++ii) acc += sr[ii]*W[(size_t)(i0+ii)*C + t]; }
        __syncthreads();
    }
    if (t<C) lg[t]=acc;
    __syncthreads();
    if (t==0){
        float m=lg[0]; for(int c2=1;c2<C;c2++) m=fmaxf(m,lg[c2]);
        float s=0.f; for(int c2=0;c2<C;c2++) s+=expf(lg[c2]-m);
        mred[0]=m; mred[1]=s;
    }
    __syncthreads();
    if (t<C) Y[((size_t)k*B+b)*C + t] = expf(lg[t]-mred[0])/mred[1];
}

__global__ void k_curr_action(const float* __restrict__ Y, float* __restrict__ outca){
    int i = blockIdx.x*256+threadIdx.x; if (i>=B*C) return;
    int b=i/C, c2=i%C;
    outca[i] = Y[((size_t)0*B+b)*C+c2] + Y[((size_t)1*B+b)*C+c2] + Y[((size_t)2*B+b)*C+c2];
}

__global__ void k_featgather(const float* __restrict__ Y, const float* __restrict__ S,
                             const float* __restrict__ R, float* __restrict__ feat){
    int idx = blockIdx.x*256+threadIdx.x; if (idx>=B*FEATP) return;
    int m = idx/FEATP, i = idx%FEATP;
    float v = 0.f;
    if (i < K*C){
        v = Y[((size_t)(i/C)*B+m)*C + (i%C)];
    } else if (i < K*C + K*D){
        int ii = i - K*C;
        v = S[((size_t)(ii>>10)*B+m)*D + (ii&1023)];
    } else if (i < FEAT){
        int ii = i - K*C - K*D;
        v = R[((size_t)(ii>>10)*B+m)*D + (ii&1023)];
    }
    feat[idx]=v;
}

__global__ void k_dur0(const float* __restrict__ R, const float* __restrict__ durW,
                       const float* __restrict__ durb, float* __restrict__ outpad){
    int b = blockIdx.x; int t = threadIdx.x;
    __shared__ float red[256];
    float p=0.f;
    for (int i=t; i<K*D; i+=256){ int k=i>>10, d=i&1023; p += R[((size_t)k*B+b)*D+d]*durW[i]; }
    red[t]=p; __syncthreads();
    for (int s=128;s>0;s>>=1){ if(t<s) red[t]+=red[t+s]; __syncthreads(); }
    if (t==0) outpad[(size_t)b*(T+1)] = red[0] + durb[0];
}

__global__ void k_red(float* __restrict__ dst, const float* __restrict__ src, int parts, size_t pstride,
                      int M, int Nld, int Nvalid, const float* __restrict__ bias){
    int idx = blockIdx.x*256+threadIdx.x;
    if (idx >= M*Nld) return;
    int n = idx % Nld;
    float v = 0.f;
    if (n < Nvalid){
        for (int p=0;p<parts;p++) v += src[(size_t)p*pstride + idx];
        if (bias) v += bias[n];
    }
    dst[idx]=v;
}

// ---------------- per-step post ----------------
__global__ void k_post(const float* __restrict__ Z0, const float* __restrict__ Z1,
                       const float* __restrict__ biascat,
                       const float* __restrict__ S, const float* __restrict__ hold,
                       const float* __restrict__ Wdur, const float* __restrict__ bdur,
                       float* __restrict__ outlab, float* __restrict__ outprobs,
                       float* __restrict__ outatt, float* __restrict__ outpad,
                       int* __restrict__ labs, float* __restrict__ wsdur, int tstep)
{
    int b=blockIdx.x, t=threadIdx.x;
    __shared__ float red[256];
    __shared__ float lg[C];
    __shared__ float sm2[2];
    __shared__ float aw[3];
    size_t zb = (size_t)b*NZ;
    if (t<C) lg[t]=Z0[zb+t]+Z1[zb+t]+biascat[t];
    __syncthreads();
    if (t==0){
        float m=lg[0]; int best=0;
        for (int c2=1;c2<C;c2++) if (lg[c2]>m){m=lg[c2];best=c2;}
        float s=0.f; for (int c2=0;c2<C;c2++) s+=expf(lg[c2]-m);
        sm2[0]=m; sm2[1]=s; labs[b]=best;
        outlab[(size_t)tstep*B+b]=(float)best;
    }
    __syncthreads();
    if (t<C) outprobs[(size_t)b*(T*C)+tstep*C+t]=expf(lg[t]-sm2[0])/sm2[1];
    const float* S0 = S + (size_t)b*D;
    const float* S1 = S0 + (size_t)B*D;
    const float* S2 = S1 + (size_t)B*D;
    float pv[3]={0.f,0.f,0.f};
    for (int d=t; d<D; d+=256){
        float qd = Z0[zb+C+d]+Z1[zb+C+d];
        pv[0]+=qd*S0[d]; pv[1]+=qd*S1[d]; pv[2]+=qd*S2[d];
    }
    for (int k=0;k<3;k++){
        red[t]=pv[k]; __syncthreads();
        for (int s=128;s>0;s>>=1){ if (t<s) red[t]+=red[t+s]; __syncthreads(); }
        if (t==0) aw[k]=red[0];
        __syncthreads();
    }
    if (t==0){
        float m=fmaxf(aw[0],fmaxf(aw[1],aw[2]));
        float e0=expf(aw[0]-m), e1=expf(aw[1]-m), e2=expf(aw[2]-m);
        float s=e0+e1+e2;
        aw[0]=e0/s; aw[1]=e1/s; aw[2]=e2/s;
    }
    __syncthreads();
    float a0=aw[0],a1=aw[1],a2=aw[2];
    float dp=0.f;
    for (int d=t; d<D; d+=256){
        float av=a0*S0[d]+a1*S1[d]+a2*S2[d];
        outatt[(size_t)tstep*B*D + (size_t)b*D + d]=av;
        dp+=av*Wdur[d];
    }
    if (hold){ for (int p=t;p<H;p+=256) dp += hold[(size_t)b*H+p]*Wdur[D+p]; }
    red[t]=dp; __syncthreads();
    for (int s=128;s>0;s>>=1){ if (t<s) red[t]+=red[t+s]; __syncthreads(); }
    if (t==0){ float dv=red[0]+bdur[0]; outpad[(size_t)b*(T+1)+tstep+1]=dv; wsdur[b]=dv; }
}

// ---------------- host ----------------

extern "C" void kernel_launch(void* const* d_in, const int* in_sizes, int n_in,
                              void* d_out, int out_size, void* d_ws, size_t ws_size,
                              hipStream_t stream) {
    const float* S    = (const float*)d_in[0];
    const float* R    = (const float*)d_in[1];
    const float* clsW = (const float*)d_in[2];
    const float* clsb = (const float*)d_in[3];
    const float* durW = (const float*)d_in[4];
    const float* durb = (const float*)d_in[5];
    const float* linW = (const float*)d_in[6];
    const float* linb = (const float*)d_in[7];
    const float* Wih  = (const float*)d_in[8];
    const float* Whh  = (const float*)d_in[9];
    const float* bih  = (const float*)d_in[10];
    const float* bhh  = (const float*)d_in[11];
    const float* Wp   = (const float*)d_in[12];
    const float* bp   = (const float*)d_in[13];
    const float* Wdur = (const float*)d_in[14];
    const float* bdur = (const float*)d_in[15];
    const float* embed= (const float*)d_in[16];
    const float* Wattn= (const float*)d_in[17];

    float* out = (float*)d_out;
    float* outlab   = out;                 // [T,B]
    float* outprobs = out + 12800;         // [B,T,C]
    float* outca    = out + 627200;        // [B,C]
    float* outpad   = out + 651776;        // [B,T+1]
    float* outatt   = out + 665088;        // [T,B,D]

    float* ws = (float*)d_ws;
    float* Z0      = ws + 0;               // 548864 (aliases WihTp rows 0..535, setup-dead)
    float* Z1      = ws + 548864;          // ends 1097728 < 2097152 (wl row untouched)
    float* WihTp   = ws + 0;               // 1025*2048 (setup only; row 1024 = wl persists)
    float* wl      = ws + 2097152;         // = WihTp + 1024*2048
    float* WhhTp   = ws + 2099200;         // 1048576
    float* Wcat    = ws + 3147776;         // 548864
    float* biascat = ws + 3696640;         // 1088
    float* bias2p  = ws + 3697728;         // 2048
    float* Y       = ws + 3699776;         // 73728
    float* Eperm   = ws + 3773504;         // 98304
    float* gx0p    = ws + 3871808;         // 1048576
    float* hA      = ws + 4920384;         // 262144
    float* hB      = ws + 5182528;         // 262144
    float* c       = ws + 5444672;         // 262144
    float* wsdur   = ws + 5706816;         // 512
    int*   labs    = (int*)(ws + 5707328); // 512
    float* feat    = ws + 5707840;         // 3227648, ends 8935488
    float* x0part  = ws + 8935488;         // 2105344, ends 11040832
    float* x0p     = ws + 11040832;        // 526336, ends 11567168
    float* gxp     = feat;                 // alias (feat dead after x0 GEMM)
    float* Epart   = x0part;               // alias (x0part dead after its reduce)

    // ---- setup ----
    k_trans_perm<<<(G4H*DP1+255)/256,256,0,stream>>>(Wih, WihTp, DP1);
    k_trans_perm<<<(G4H*H+255)/256,256,0,stream>>>(Whh, WhhTp, H);
    k_prep<<<(H*NZ+255)/256,256,0,stream>>>(bih,bhh,Wp,bp,Wattn,bias2p,Wcat,biascat);
    k_cls<<<K*B,64,0,stream>>>(S,R,clsW,clsb,Y);
    k_curr_action<<<(B*C+255)/256,256,0,stream>>>(Y,outca);
    k_featgather<<<(B*FEATP+255)/256,256,0,stream>>>(Y,S,R,feat);
    k_dur0<<<B,256,0,stream>>>(R,durW,durb,outpad);
    k_gemm2<<<dim3(16,17,4),256,0,stream>>>(feat, linW, x0part, B, DP1, FEAT, FEATP, DP1, 1028,
                                            1572, (size_t)B*1028, 1, 0);
    k_red<<<(B*1028+255)/256,256,0,stream>>>(x0p, x0part, 4, (size_t)B*1028, B, 1028, DP1, linb);
    k_gemm2<<<dim3(16,32,2),256,0,stream>>>(x0p, WihTp, gxp, B, G4H, DP1, 1028, G4H, G4H,
                                            512, (size_t)B*G4H, 1, 1);
    k_red<<<(B*G4H+255)/256,256,0,stream>>>(gx0p, gxp, 2, (size_t)B*G4H, B, G4H, G4H, bias2p);
    k_gemm2<<<dim3(2,32,4),256,0,stream>>>(embed, WihTp, Epart, C, G4H, D, D, G4H, G4H,
                                           256, (size_t)C*G4H, 1, 1);
    k_red<<<(C*G4H+255)/256,256,0,stream>>>(Eperm, Epart, 4, (size_t)C*G4H, C, G4H, G4H, bias2p);

    // ---- scan ----
    float* hOld=hA; float* hNew=hB;
    for (int t=0;t<T;t++){
        if (t==0){
            k_lstm0<<<(B*H+255)/256,256,0,stream>>>(gx0p, c, hNew);
        } else {
            k_gates_lstm<<<dim3(16,32),256,0,stream>>>(hOld, WhhTp, Eperm, wl, labs, wsdur, c, hNew);
        }
        k_gemm2<<<dim3(16,17,2),256,0,stream>>>(hNew, Wcat, Z0, B, NZ, H, H, NZ, NZ,
                                                256, (size_t)B*NZ, 1, 1);
        k_post<<<B,256,0,stream>>>(Z0,Z1,biascat,S,(t==0)?nullptr:hOld,Wdur,bdur,
                                   outlab,outprobs,outatt,outpad,labs,wsdur,t);
        float* tmp=hOld; hOld=hNew; hNew=tmp;
    }
}

// Round 4
// 1604.130 us; speedup vs baseline: 4.6543x; 1.1878x over previous
//
#include <hip/hip_runtime.h>
#include <math.h>

#define B 512
#define D 1024
#define H 512
#define C 48
#define K 3
#define T 25
#define DP1 1025
#define FEAT 6288
#define FEATP 6304      // padded feat ld
#define G4H 2048
#define NC 3120         // combined step-GEMM N = 2048 (gates) + 48 (logits) + 1024 (q)
#define PST 1597440     // rawgZ part stride = 512*3120

__device__ __forceinline__ float sigf(float x){ return 1.0f/(1.0f+expf(-x)); }

// ---------------- GEMM core: 64x64 tile, 4x4 micro-tile, BK=16, 256 threads ----------------

__device__ __forceinline__ void g4_load(
    const float* __restrict__ A, const float* __restrict__ Bm,
    int M, int N, int kcnt, int lda, int ldb,
    int m0, int n0, int koff, int avec, int bvec, int t,
    float4& ra, float4& rb)
{
    int am = t & 63, ak = (t>>6)<<2;
    int m = m0 + am, kA = koff + ak;
    if (m < M && avec && (kA+3) < kcnt){
        ra = *(const float4*)&A[(size_t)m*lda + kA];
    } else {
        float* rp=(float*)&ra;
        #pragma unroll
        for(int i=0;i<4;i++) rp[i] = (m<M && (kA+i)<kcnt)? A[(size_t)m*lda+kA+i] : 0.f;
    }
    int bk = t>>4, bn = (t&15)<<2;
    int kB = koff + bk, n = n0 + bn;
    if (kB < kcnt && bvec && (n+3) < N){
        rb = *(const float4*)&Bm[(size_t)kB*ldb + n];
    } else {
        float* rp=(float*)&rb;
        #pragma unroll
        for(int i=0;i<4;i++) rp[i] = (kB<kcnt && (n+i)<N)? Bm[(size_t)kB*ldb+n+i] : 0.f;
    }
}

__device__ __forceinline__ void gemm_core4(
    const float* __restrict__ A, const float* __restrict__ Bm,
    int M, int N, int kcnt, int lda, int ldb,
    int m0, int n0, int avec, int bvec, int t,
    float (* __restrict__ As)[64], float (* __restrict__ Bs)[64],
    float acc[4][4])
{
    float4 ra, rb;
    g4_load(A,Bm,M,N,kcnt,lda,ldb,m0,n0,0,avec,bvec,t,ra,rb);
    int nIter = (kcnt+15)>>4;
    int am=t&63, ak=(t>>6)<<2, bk=t>>4, bn=(t&15)<<2;
    int r0=(t>>4)<<2, c0=(t&15)<<2;
    for (int it=0; it<nIter; ++it){
        const float* rp=(const float*)&ra;
        #pragma unroll
        for (int i=0;i<4;i++) As[ak+i][am]=rp[i];
        *(float4*)&Bs[bk][bn]=rb;
        __syncthreads();
        if (it+1<nIter) g4_load(A,Bm,M,N,kcnt,lda,ldb,m0,n0,(it+1)<<4,avec,bvec,t,ra,rb);
        #pragma unroll
        for (int kk=0;kk<16;++kk){
            float4 av=*(const float4*)&As[kk][r0];
            float4 bv=*(const float4*)&Bs[kk][c0];
            acc[0][0]+=av.x*bv.x; acc[0][1]+=av.x*bv.y; acc[0][2]+=av.x*bv.z; acc[0][3]+=av.x*bv.w;
            acc[1][0]+=av.y*bv.x; acc[1][1]+=av.y*bv.y; acc[1][2]+=av.y*bv.z; acc[1][3]+=av.y*bv.w;
            acc[2][0]+=av.z*bv.x; acc[2][1]+=av.z*bv.y; acc[2][2]+=av.z*bv.z; acc[2][3]+=av.z*bv.w;
            acc[3][0]+=av.w*bv.x; acc[3][1]+=av.w*bv.y; acc[3][2]+=av.w*bv.z; acc[3][3]+=av.w*bv.w;
        }
        __syncthreads();
    }
}

__global__ __launch_bounds__(256)
void k_gemm4(const float* __restrict__ A, const float* __restrict__ Bm, float* __restrict__ Cc,
             int M, int N, int Ktot, int lda, int ldb, int ldc, int Nvalid,
             int ksl, size_t cstride, int avec, int bvec)
{
    __shared__ __align__(16) float As[16][64];
    __shared__ __align__(16) float Bs[16][64];
    int t = threadIdx.x;
    int m0 = blockIdx.x*64, n0 = blockIdx.y*64;
    int z = blockIdx.z;
    int kbase = z*ksl;
    int kcnt = (z == (int)gridDim.z-1) ? (Ktot - kbase) : ksl;
    const float* Az = A + kbase;
    const float* Bz = Bm + (size_t)kbase*ldb;
    float acc[4][4] = {};
    gemm_core4(Az,Bz,M,N,kcnt,lda,ldb,m0,n0,avec,bvec,t,As,Bs,acc);
    float* Cz = Cc + (size_t)z*cstride;
    int r0=(t>>4)<<2, c0=(t&15)<<2;
    int nb = n0+c0;
    #pragma unroll
    for (int i=0;i<4;i++){
        int r = m0+r0+i;
        if (r>=M) continue;
        float* crow = &Cz[(size_t)r*ldc];
        if (nb+3 < Nvalid){
            float4 v; v.x=acc[i][0]; v.y=acc[i][1]; v.z=acc[i][2]; v.w=acc[i][3];
            *(float4*)&crow[nb] = v;
        } else {
            #pragma unroll
            for (int j=0;j<4;j++) if (nb+j < Nvalid) crow[nb+j]=acc[i][j];
        }
    }
}

// ---------------- setup kernels ----------------

// bias2p (gate-perm), biascat (logits bias), wl (perm last-col of W_ih)
__global__ void k_prep(const float* __restrict__ bih, const float* __restrict__ bhh,
                       const float* __restrict__ bp, const float* __restrict__ Wih,
                       float* __restrict__ bias2p, float* __restrict__ biascat,
                       float* __restrict__ wl){
    int i = blockIdx.x*256 + threadIdx.x;
    if (i < G4H){
        int g=i&3, j=i>>2; int gi=(g<<9)|j;
        bias2p[i]=bih[gi]+bhh[gi];
        wl[i]=Wih[(size_t)gi*DP1 + 1024];
    }
    if (i < C) biascat[i]=bp[i];
}

// Wcomb[512][3120] = [Whh^T perm | Wp | Wattn/32]
__global__ void k_build_wcomb(const float* __restrict__ Whh, const float* __restrict__ Wp,
                              const float* __restrict__ Wattn, float* __restrict__ Wcomb){
    int idx = blockIdx.x*256+threadIdx.x;
    if (idx >= H*NC) return;
    int k2 = idx/NC, col = idx%NC;
    float v;
    if (col < G4H){ int j=col>>2, g=col&3; v = Whh[((size_t)((g<<9)|j))*H + k2]; }
    else if (col < G4H+C){ v = Wp[k2*C + (col-G4H)]; }
    else { v = Wattn[(size_t)k2*D + (col-G4H-C)] * 0.03125f; }
    Wcomb[idx]=v;
}

// W_ih^T with gate-perm columns: dst[k2*2048 + (j*4+g)] = Wih[(g*512+j)*1025 + k2]
__global__ void k_trans_perm(const float* __restrict__ src, float* __restrict__ dst, int cols){
    int idx = blockIdx.x*256+threadIdx.x;
    if (idx >= G4H*cols) return;
    int gi = idx / cols, k2 = idx % cols;
    int g = gi >> 9, j = gi & 511;
    dst[(size_t)k2*G4H + ((j<<2) | g)] = src[idx];
}

__global__ void k_cls(const float* __restrict__ S, const float* __restrict__ R,
                      const float* __restrict__ clsW, const float* __restrict__ clsb,
                      float* __restrict__ Y){
    int kb = blockIdx.x; int k = kb / B; int b = kb % B;
    int t = threadIdx.x; // 64
    __shared__ float sr[64];
    __shared__ float lg[C];
    __shared__ float mred[2];
    float acc = (t<C) ? clsb[k*C+t] : 0.f;
    const float* W = clsW + (size_t)k*2*D*C;
    for (int i0=0; i0<2*D; i0+=64){
        int i = i0 + t;
        sr[t] = (i < D) ? S[((size_t)k*B+b)*D + i] : R[((size_t)k*B+b)*D + (i-D)];
        __syncthreads();
        if (t < C){ for (int ii=0; ii<64; ++ii) acc += sr[ii]*W[(size_t)(i0+ii)*C + t]; }
        __syncthreads();
    }
    if (t<C) lg[t]=acc;
    __syncthreads();
    if (t==0){
        float m=lg[0]; for(int c2=1;c2<C;c2++) m=fmaxf(m,lg[c2]);
        float s=0.f; for(int c2=0;c2<C;c2++) s+=expf(lg[c2]-m);
        mred[0]=m; mred[1]=s;
    }
    __syncthreads();
    if (t<C) Y[((size_t)k*B+b)*C + t] = expf(lg[t]-mred[0])/mred[1];
}

__global__ void k_curr_action(const float* __restrict__ Y, float* __restrict__ outca){
    int i = blockIdx.x*256+threadIdx.x; if (i>=B*C) return;
    int b=i/C, c2=i%C;
    outca[i] = Y[((size_t)0*B+b)*C+c2] + Y[((size_t)1*B+b)*C+c2] + Y[((size_t)2*B+b)*C+c2];
}

__global__ void k_featgather(const float* __restrict__ Y, const float* __restrict__ S,
                             const float* __restrict__ R, float* __restrict__ feat){
    int idx = blockIdx.x*256+threadIdx.x; if (idx>=B*FEATP) return;
    int m = idx/FEATP, i = idx%FEATP;
    float v = 0.f;
    if (i < K*C){
        v = Y[((size_t)(i/C)*B+m)*C + (i%C)];
    } else if (i < K*C + K*D){
        int ii = i - K*C;
        v = S[((size_t)(ii>>10)*B+m)*D + (ii&1023)];
    } else if (i < FEAT){
        int ii = i - K*C - K*D;
        v = R[((size_t)(ii>>10)*B+m)*D + (ii&1023)];
    }
    feat[idx]=v;
}

__global__ void k_dur0(const float* __restrict__ R, const float* __restrict__ durW,
                       const float* __restrict__ durb, float* __restrict__ outpad){
    int b = blockIdx.x; int t = threadIdx.x;
    __shared__ float red[256];
    float p=0.f;
    for (int i=t; i<K*D; i+=256){ int k=i>>10, d=i&1023; p += R[((size_t)k*B+b)*D+d]*durW[i]; }
    red[t]=p; __syncthreads();
    for (int s=128;s>0;s>>=1){ if(t<s) red[t]+=red[t+s]; __syncthreads(); }
    if (t==0) outpad[(size_t)b*(T+1)] = red[0] + durb[0];
}

__global__ void k_red(float* __restrict__ dst, const float* __restrict__ src, int parts, size_t pstride,
                      int M, int Nld, int Nvalid, const float* __restrict__ bias){
    int idx = blockIdx.x*256+threadIdx.x;
    if (idx >= M*Nld) return;
    int n = idx % Nld;
    float v = 0.f;
    if (n < Nvalid){
        for (int p=0;p<parts;p++) v += src[(size_t)p*pstride + idx];
        if (bias) v += bias[n];
    }
    dst[idx]=v;
}

// ---------------- scan kernels ----------------

// t=0: h0,c0 from gx0_perm (4 gates contiguous per hidden unit)
__global__ void k_lstm0(const float* __restrict__ gx0, float* __restrict__ c, float* __restrict__ h){
    int idx = blockIdx.x*256+threadIdx.x; if (idx>=B*H) return;
    int r=idx>>9, j=idx&511;
    float4 g = *(const float4*)&gx0[(size_t)r*G4H + (j<<2)];
    float cn = sigf(g.x)*tanhf(g.z);
    c[idx]=cn; h[idx]=sigf(g.w)*tanhf(cn);
}

// apply LSTM from combined-GEMM raw gates (2 split-K parts) + E[lab] + dur*wl
__global__ void k_apply(const float* __restrict__ Zb, const float* __restrict__ E,
                        const float* __restrict__ wl, const int* __restrict__ labs,
                        const float* __restrict__ dur, float* __restrict__ c,
                        float* __restrict__ hN){
    int idx = blockIdx.x*256+threadIdx.x; if (idx>=B*H) return;
    int r=idx>>9, j=idx&511, p=j<<2;
    float4 g0 = *(const float4*)&Zb[(size_t)r*NC + p];
    float4 g1 = *(const float4*)&Zb[(size_t)r*NC + p + PST];
    int lb=labs[r]; float dv=dur[r];
    float4 e4 = *(const float4*)&E[(size_t)lb*G4H + p];
    float4 w4 = *(const float4*)&wl[p];
    float gi_=g0.x+g1.x+e4.x+dv*w4.x;
    float gf_=g0.y+g1.y+e4.y+dv*w4.y;
    float gg_=g0.z+g1.z+e4.z+dv*w4.z;
    float go_=g0.w+g1.w+e4.w+dv*w4.w;
    float cn = sigf(gf_)*c[idx] + sigf(gi_)*tanhf(gg_);
    c[idx]=cn;
    hN[idx]=sigf(go_)*tanhf(cn);
}

// softmax/argmax + attention + dur head; Z cols live at rawgZ[b*3120 + 2048 + ...]
__global__ void k_post(const float* __restrict__ Zb, const float* __restrict__ S,
                       const float* __restrict__ hold, const float* __restrict__ biascat,
                       const float* __restrict__ Wdur, const float* __restrict__ bdur,
                       float* __restrict__ outlab, float* __restrict__ outprobs,
                       float* __restrict__ outatt, float* __restrict__ outpad,
                       int* __restrict__ labs, float* __restrict__ wsdur, int tstep)
{
    int b=blockIdx.x, t=threadIdx.x;
    __shared__ float red[256];
    __shared__ float lg[C];
    __shared__ float sm2[2];
    __shared__ float aw[3];
    size_t zr = (size_t)b*NC + G4H;
    if (t<C) lg[t]=Zb[zr+t]+Zb[zr+t+PST]+biascat[t];
    __syncthreads();
    if (t==0){
        float m=lg[0]; int best=0;
        for (int c2=1;c2<C;c2++) if (lg[c2]>m){m=lg[c2];best=c2;}
        float s=0.f; for (int c2=0;c2<C;c2++) s+=expf(lg[c2]-m);
        sm2[0]=m; sm2[1]=s; labs[b]=best;
        outlab[(size_t)tstep*B+b]=(float)best;
    }
    __syncthreads();
    if (t<C) outprobs[(size_t)b*(T*C)+tstep*C+t]=expf(lg[t]-sm2[0])/sm2[1];
    const float* S0 = S + (size_t)b*D;
    const float* S1 = S0 + (size_t)B*D;
    const float* S2 = S1 + (size_t)B*D;
    float pv[3]={0.f,0.f,0.f};
    for (int d=t; d<D; d+=256){
        float qd = Zb[zr+C+d]+Zb[zr+C+d+PST];
        pv[0]+=qd*S0[d]; pv[1]+=qd*S1[d]; pv[2]+=qd*S2[d];
    }
    for (int k=0;k<3;k++){
        red[t]=pv[k]; __syncthreads();
        for (int s=128;s>0;s>>=1){ if (t<s) red[t]+=red[t+s]; __syncthreads(); }
        if (t==0) aw[k]=red[0];
        __syncthreads();
    }
    if (t==0){
        float m=fmaxf(aw[0],fmaxf(aw[1],aw[2]));
        float e0=expf(aw[0]-m), e1=expf(aw[1]-m), e2=expf(aw[2]-m);
        float s=e0+e1+e2;
        aw[0]=e0/s; aw[1]=e1/s; aw[2]=e2/s;
    }
    __syncthreads();
    float a0=aw[0],a1=aw[1],a2=aw[2];
    float dp=0.f;
    for (int d=t; d<D; d+=256){
        float av=a0*S0[d]+a1*S1[d]+a2*S2[d];
        outatt[(size_t)tstep*B*D + (size_t)b*D + d]=av;
        dp+=av*Wdur[d];
    }
    if (hold){ for (int p=t;p<H;p+=256) dp += hold[(size_t)b*H+p]*Wdur[D+p]; }
    red[t]=dp; __syncthreads();
    for (int s=128;s>0;s>>=1){ if (t<s) red[t]+=red[t+s]; __syncthreads(); }
    if (t==0){ float dv=red[0]+bdur[0]; outpad[(size_t)b*(T+1)+tstep+1]=dv; wsdur[b]=dv; }
}

// ---------------- host ----------------

extern "C" void kernel_launch(void* const* d_in, const int* in_sizes, int n_in,
                              void* d_out, int out_size, void* d_ws, size_t ws_size,
                              hipStream_t stream) {
    const float* S    = (const float*)d_in[0];
    const float* R    = (const float*)d_in[1];
    const float* clsW = (const float*)d_in[2];
    const float* clsb = (const float*)d_in[3];
    const float* durW = (const float*)d_in[4];
    const float* durb = (const float*)d_in[5];
    const float* linW = (const float*)d_in[6];
    const float* linb = (const float*)d_in[7];
    const float* Wih  = (const float*)d_in[8];
    const float* Whh  = (const float*)d_in[9];
    const float* bih  = (const float*)d_in[10];
    const float* bhh  = (const float*)d_in[11];
    const float* Wp   = (const float*)d_in[12];
    const float* bp   = (const float*)d_in[13];
    const float* Wdur = (const float*)d_in[14];
    const float* bdur = (const float*)d_in[15];
    const float* embed= (const float*)d_in[16];
    const float* Wattn= (const float*)d_in[17];

    float* out = (float*)d_out;
    float* outlab   = out;                 // [T,B]
    float* outprobs = out + 12800;         // [B,T,C]
    float* outca    = out + 627200;        // [B,C]
    float* outpad   = out + 651776;        // [B,T+1]
    float* outatt   = out + 665088;        // [T,B,D]

    float* ws = (float*)d_ws;
    float* Wcomb   = ws + 0;               // 1,597,440
    float* E       = ws + 1597440;         // 98,304
    float* wl      = ws + 1695744;         // 2,048
    float* bias2p  = ws + 1697792;         // 2,048
    float* biascat = ws + 1699840;         // 64
    float* hA      = ws + 1699904;         // 262,144
    float* hB      = ws + 1962048;         // 262,144
    float* c       = ws + 2224192;         // 262,144
    float* wsdur   = ws + 2486336;         // 512
    int*   labs    = (int*)(ws + 2486848); // 512
    float* rawgZ   = ws + 2487360;         // 2 × 1,597,440 = 3,194,880 (scan; setup scratch)
    float* Y       = ws + 5682240;         // 73,728
    float* featWT  = ws + 5755968;         // 3,227,648 (feat, then WihTp alias)
    float* x0p     = ws + 8983616;         // 526,336
    float* gx0p    = ws + 9509952;         // 1,048,576 -> end 10,558,528 floats (42.2 MB)

    float* feat   = featWT;
    float* WihTp  = featWT;                // built after feat is dead
    float* x0part = rawgZ;                 // 6 × 526,336 = 3,158,016 <= 3,194,880
    float* gxpart = rawgZ;                 // 2 × 1,048,576
    float* Epart  = rawgZ;                 // 4 × 98,304

    // ---- setup ----
    k_prep<<<(G4H+255)/256,256,0,stream>>>(bih,bhh,bp,Wih,bias2p,biascat,wl);
    k_build_wcomb<<<(H*NC+255)/256,256,0,stream>>>(Whh,Wp,Wattn,Wcomb);
    k_cls<<<K*B,64,0,stream>>>(S,R,clsW,clsb,Y);
    k_curr_action<<<(B*C+255)/256,256,0,stream>>>(Y,outca);
    k_featgather<<<(B*FEATP+255)/256,256,0,stream>>>(Y,S,R,feat);
    k_dur0<<<B,256,0,stream>>>(R,durW,durb,outpad);
    // x0 = feat @ linW (split-K 6)
    k_gemm4<<<dim3(8,17,6),256,0,stream>>>(feat, linW, x0part, B, DP1, FEATP, FEATP, DP1, 1028, 1028,
                                           1056, (size_t)B*1028, 1, 0);
    k_red<<<(B*1028+255)/256,256,0,stream>>>(x0p, x0part, 6, (size_t)B*1028, B, 1028, DP1, linb);
    // WihTp (feat now dead)
    k_trans_perm<<<(G4H*DP1+255)/256,256,0,stream>>>(Wih, WihTp, DP1);
    // gx0_perm = x0 @ WihTp (split-K 2) + bias2p
    k_gemm4<<<dim3(8,32,2),256,0,stream>>>(x0p, WihTp, gxpart, B, G4H, DP1, 1028, G4H, G4H, G4H,
                                           516, (size_t)B*G4H, 1, 1);
    k_red<<<(B*G4H+255)/256,256,0,stream>>>(gx0p, gxpart, 2, (size_t)B*G4H, B, G4H, G4H, bias2p);
    // E_perm = embed @ WihTp[0:1024,:] (split-K 4) + bias2p
    k_gemm4<<<dim3(1,32,4),256,0,stream>>>(embed, WihTp, Epart, C, G4H, D, D, G4H, G4H, G4H,
                                           256, (size_t)C*G4H, 1, 1);
    k_red<<<(C*G4H+255)/256,256,0,stream>>>(E, Epart, 4, (size_t)C*G4H, C, G4H, G4H, bias2p);
    // h0, c0
    k_lstm0<<<(B*H+255)/256,256,0,stream>>>(gx0p, c, hA);

    // ---- scan ----
    float* hCur=hA; float* hPrev=hB;   // hPrev buffer reused as hNext each step
    for (int t=0;t<T;t++){
        // rawgZ = hCur @ Wcomb  (split-K 2; gates cols 0..2047, logits 2048..2095, q 2096..3119)
        k_gemm4<<<dim3(8,49,2),256,0,stream>>>(hCur, Wcomb, rawgZ, B, NC, H, H, NC, NC, NC,
                                               256, (size_t)PST, 1, 1);
        k_post<<<B,256,0,stream>>>(rawgZ,S,(t==0)?nullptr:hPrev,biascat,Wdur,bdur,
                                   outlab,outprobs,outatt,outpad,labs,wsdur,t);
        if (t<T-1){
            k_apply<<<(B*H+255)/256,256,0,stream>>>(rawgZ,E,wl,labs,wsdur,c,hPrev); // hPrev becomes h_{t+1}
            float* tmp=hPrev; hPrev=hCur; hCur=tmp;
        }
    }
}

// Round 5
// 1127.775 us; speedup vs baseline: 6.6201x; 1.4224x over previous
//
#include <hip/hip_runtime.h>
#include <math.h>

#define B 512
#define D 1024
#define H 512
#define C 48
#define K 3
#define T 25
#define DP1 1025
#define G4H 2048
#define NC 3120         // step GEMM N: 2048 gates | 48 logits | 1024 q
#define KP 1056         // padded K for x0/embed rows (multiple of 32)
#define FK 6304         // padded feat-K (6288 -> 6304)

typedef _Float16 f16;
typedef _Float16 half8 __attribute__((ext_vector_type(8)));
typedef float floatx4 __attribute__((ext_vector_type(4)));

__device__ __forceinline__ float sigf(float x){ return 1.0f/(1.0f+expf(-x)); }

// ================= split-f16 MFMA GEMM: 64x64 tile, BK=32, 4 waves =================
// A as hi/lo f16 [M][lda] k-contig (MODE 0) or gathered from Y(bf->f16 pair)/S/R (MODE 1, x0).
// B as hi/lo f16 [Nrows][ldb] k-contig (pre-transposed; rows padded/zeroed).
// C fp32 [M][ldc] (+bias), optional split-K via blockIdx.z (partials at z*cstride).

template<int MODE>
__device__ __forceinline__ void mf_load(
    const f16* __restrict__ Ahi, const f16* __restrict__ Alo,
    const f16* __restrict__ Bhi, const f16* __restrict__ Blo,
    int M, int lda, int ldb, int m0, int n0, int kbase, int k0, int t,
    const f16* __restrict__ Yh, const f16* __restrict__ Yl,
    const float* __restrict__ Sf, const float* __restrict__ Rf,
    half8& rah, half8& ral, half8& rbh, half8& rbl)
{
    int r = t>>2, seg = t&3;
    int kk = k0 + seg*8;
    {
        size_t off = (size_t)(n0+r)*ldb + kbase + kk;
        rbh = *(const half8*)(Bhi + off);
        rbl = *(const half8*)(Blo + off);
    }
    int m = m0 + r;
    if (MODE==0){
        if (m < M){
            size_t off = (size_t)m*lda + kbase + kk;
            rah = *(const half8*)(Ahi + off);
            ral = *(const half8*)(Alo + off);
        } else {
            #pragma unroll
            for (int i=0;i<8;i++){ rah[i]=(f16)0; ral[i]=(f16)0; }
        }
    } else {
        int kabs = kbase + kk;   // 8-aligned; source runs never straddle boundaries
        if (kabs < 144){
            rah = *(const half8*)(Yh + (size_t)m*144 + kabs);
            ral = *(const half8*)(Yl + (size_t)m*144 + kabs);
        } else if (kabs < 6288){
            int kp = kabs - 144;
            const float* src = (kp < 3*D)
                ? (Sf + (size_t)(kp>>10)*(B*D) + (size_t)m*D + (kp&(D-1)))
                : (Rf + (size_t)((kp-3*D)>>10)*(B*D) + (size_t)m*D + ((kp-3*D)&(D-1)));
            float4 f0 = *(const float4*)src;
            float4 f1 = *(const float4*)(src+4);
            float fv[8]={f0.x,f0.y,f0.z,f0.w,f1.x,f1.y,f1.z,f1.w};
            #pragma unroll
            for (int i=0;i<8;i++){
                f16 h=(f16)fv[i];
                rah[i]=h; ral[i]=(f16)(fv[i]-(float)h);
            }
        } else {
            #pragma unroll
            for (int i=0;i<8;i++){ rah[i]=(f16)0; ral[i]=(f16)0; }
        }
    }
}

template<int MODE>
__global__ __launch_bounds__(256)
void k_mfma(const f16* __restrict__ Ahi, const f16* __restrict__ Alo,
            const f16* __restrict__ Bhi, const f16* __restrict__ Blo,
            float* __restrict__ Cc, const float* __restrict__ bias,
            int M, int Nvalid, int Ktot, int lda, int ldb, int ldc,
            int ksl, size_t cstride,
            const f16* __restrict__ Yh, const f16* __restrict__ Yl,
            const float* __restrict__ Sf, const float* __restrict__ Rf)
{
    __shared__ __align__(16) f16 Ash[64][40];   // +8 pad: conflict-free b128 frag reads
    __shared__ __align__(16) f16 Asl[64][40];
    __shared__ __align__(16) f16 Bsh[64][40];
    __shared__ __align__(16) f16 Bsl[64][40];
    int t = threadIdx.x;
    int m0 = blockIdx.x*64, n0 = blockIdx.y*64;
    int z = blockIdx.z;
    int kbase = z*ksl;
    int kcnt = (z==(int)gridDim.z-1)? (Ktot-kbase) : ksl;   // always %32==0 here
    int nIter = kcnt >> 5;
    int r = t>>2, seg = t&3;
    half8 rah, ral, rbh, rbl;
    mf_load<MODE>(Ahi,Alo,Bhi,Blo,M,lda,ldb,m0,n0,kbase,0,t,Yh,Yl,Sf,Rf,rah,ral,rbh,rbl);
    int lane = t&63, wv = t>>6;
    int lrow = lane&15, quad = lane>>4;
    floatx4 acc[4] = {};
    for (int it=0; it<nIter; ++it){
        *(half8*)&Ash[r][seg*8] = rah;
        *(half8*)&Asl[r][seg*8] = ral;
        *(half8*)&Bsh[r][seg*8] = rbh;
        *(half8*)&Bsl[r][seg*8] = rbl;
        __syncthreads();
        if (it+1 < nIter)
            mf_load<MODE>(Ahi,Alo,Bhi,Blo,M,lda,ldb,m0,n0,kbase,(it+1)<<5,t,Yh,Yl,Sf,Rf,rah,ral,rbh,rbl);
        half8 ah = *(const half8*)&Ash[wv*16+lrow][quad*8];
        half8 al = *(const half8*)&Asl[wv*16+lrow][quad*8];
        #pragma unroll
        for (int j=0;j<4;j++){
            half8 bh = *(const half8*)&Bsh[j*16+lrow][quad*8];
            half8 bl = *(const half8*)&Bsl[j*16+lrow][quad*8];
            acc[j] = __builtin_amdgcn_mfma_f32_16x16x32_f16(ah, bh, acc[j], 0,0,0);
            acc[j] = __builtin_amdgcn_mfma_f32_16x16x32_f16(al, bh, acc[j], 0,0,0);
            acc[j] = __builtin_amdgcn_mfma_f32_16x16x32_f16(ah, bl, acc[j], 0,0,0);
        }
        __syncthreads();
    }
    float* Cz = Cc + (size_t)z*cstride;
    #pragma unroll
    for (int j=0;j<4;j++){
        int col = n0 + j*16 + lrow;
        if (col >= Nvalid) continue;
        float bv = bias ? bias[col] : 0.f;
        #pragma unroll
        for (int i=0;i<4;i++){
            int row = m0 + wv*16 + quad*4 + i;
            if (row < M) Cz[(size_t)row*ldc + col] = acc[j][i] + bv;
        }
    }
}

// ================= setup kernels =================

// tiled transpose + split-f16 convert: dst hi/lo [NB][KB] from src [Ksrc][ld_src] (cols Nsrc valid)
__global__ void k_bt_build(const float* __restrict__ src, f16* __restrict__ hi, f16* __restrict__ lo,
                           int Ksrc, int Nsrc, int ld_src, int NB, int KB, float scale){
    __shared__ float tile[32][33];
    int k0 = blockIdx.x*32, n0 = blockIdx.y*32;
    int lx = threadIdx.x & 31, ly = threadIdx.x >> 5;
    for (int rr=0; rr<32; rr+=8){
        int k2 = k0+ly+rr, n = n0+lx;
        tile[ly+rr][lx] = (k2<Ksrc && n<Nsrc)? src[(size_t)k2*ld_src+n]*scale : 0.f;
    }
    __syncthreads();
    for (int rr=0; rr<32; rr+=8){
        int n = n0+ly+rr, k2 = k0+lx;
        if (n<NB && k2<KB){
            float v = tile[lx][ly+rr];
            f16 h=(f16)v;
            hi[(size_t)n*KB+k2]=h;
            lo[(size_t)n*KB+k2]=(f16)(v-(float)h);
        }
    }
}

// gate-permuted row copy + split convert: dst row p=j*4+g <- src row gi=g*512+j
__global__ void k_permrows(const float* __restrict__ src, f16* __restrict__ hi, f16* __restrict__ lo,
                           int src_ld, int dst_ld, int kvalid){
    int idx = blockIdx.x*256+threadIdx.x;
    if (idx >= G4H*dst_ld) return;
    int p = idx/dst_ld, k2 = idx%dst_ld;
    int j = p>>2, g = p&3, gi = (g<<9)|j;
    float v = (k2<kvalid)? src[(size_t)gi*src_ld + k2] : 0.f;
    f16 h=(f16)v;
    hi[idx]=h; lo[idx]=(f16)(v-(float)h);
}

__global__ void k_cvt(const float* __restrict__ src, f16* __restrict__ hi, f16* __restrict__ lo,
                      int M, int ld_src, int nvalid, int ld_dst){
    int idx = blockIdx.x*256+threadIdx.x;
    if (idx >= M*ld_dst) return;
    int m = idx/ld_dst, n = idx%ld_dst;
    float v = (n<nvalid)? src[(size_t)m*ld_src+n] : 0.f;
    f16 h=(f16)v; hi[idx]=h; lo[idx]=(f16)(v-(float)h);
}

__global__ void k_cvtY(const float* __restrict__ Y, f16* __restrict__ hi, f16* __restrict__ lo){
    int idx = blockIdx.x*256+threadIdx.x;
    if (idx >= B*144) return;
    int b = idx/144, k2 = idx%144;
    float v = Y[((size_t)(k2/C)*B + b)*C + (k2%C)];
    f16 h=(f16)v; hi[idx]=h; lo[idx]=(f16)(v-(float)h);
}

__global__ void k_zeroh(f16* a, f16* b2, int n){
    int i = blockIdx.x*256+threadIdx.x; if (i<n){ a[i]=(f16)0; b2[i]=(f16)0; }
}

__global__ void k_prep(const float* __restrict__ bih, const float* __restrict__ bhh,
                       const float* __restrict__ bp, const float* __restrict__ Wih,
                       float* __restrict__ bias2p, float* __restrict__ biascat,
                       float* __restrict__ wl){
    int i = blockIdx.x*256 + threadIdx.x;
    if (i < G4H){
        int g=i&3, j=i>>2; int gi=(g<<9)|j;
        bias2p[i]=bih[gi]+bhh[gi];
        wl[i]=Wih[(size_t)gi*DP1 + 1024];
    }
    if (i < C) biascat[i]=bp[i];
}

__global__ void k_cls(const float* __restrict__ S, const float* __restrict__ R,
                      const float* __restrict__ clsW, const float* __restrict__ clsb,
                      float* __restrict__ Y){
    int kb = blockIdx.x; int k = kb / B; int b = kb % B;
    int t = threadIdx.x; // 64
    __shared__ float sr[64];
    __shared__ float lg[C];
    __shared__ float mred[2];
    float acc = (t<C) ? clsb[k*C+t] : 0.f;
    const float* W = clsW + (size_t)k*2*D*C;
    for (int i0=0; i0<2*D; i0+=64){
        int i = i0 + t;
        sr[t] = (i < D) ? S[((size_t)k*B+b)*D + i] : R[((size_t)k*B+b)*D + (i-D)];
        __syncthreads();
        if (t < C){ for (int ii=0; ii<64; ++ii) acc += sr[ii]*W[(size_t)(i0+ii)*C + t]; }
        __syncthreads();
    }
    if (t<C) lg[t]=acc;
    __syncthreads();
    if (t==0){
        float m=lg[0]; for(int c2=1;c2<C;c2++) m=fmaxf(m,lg[c2]);
        float s=0.f; for(int c2=0;c2<C;c2++) s+=expf(lg[c2]-m);
        mred[0]=m; mred[1]=s;
    }
    __syncthreads();
    if (t<C) Y[((size_t)k*B+b)*C + t] = expf(lg[t]-mred[0])/mred[1];
}

__global__ void k_curr_action(const float* __restrict__ Y, float* __restrict__ outca){
    int i = blockIdx.x*256+threadIdx.x; if (i>=B*C) return;
    int b=i/C, c2=i%C;
    outca[i] = Y[((size_t)0*B+b)*C+c2] + Y[((size_t)1*B+b)*C+c2] + Y[((size_t)2*B+b)*C+c2];
}

__global__ void k_dur0(const float* __restrict__ R, const float* __restrict__ durW,
                       const float* __restrict__ durb, float* __restrict__ outpad){
    int b = blockIdx.x; int t = threadIdx.x;
    __shared__ float red[256];
    float p=0.f;
    for (int i=t; i<K*D; i+=256){ int k=i>>10, d=i&1023; p += R[((size_t)k*B+b)*D+d]*durW[i]; }
    red[t]=p; __syncthreads();
    for (int s=128;s>0;s>>=1){ if(t<s) red[t]+=red[t+s]; __syncthreads(); }
    if (t==0) outpad[(size_t)b*(T+1)] = red[0] + durb[0];
}

__global__ void k_red(float* __restrict__ dst, const float* __restrict__ src, int parts, size_t pstride,
                      int M, int Nld, int Nvalid, const float* __restrict__ bias){
    int idx = blockIdx.x*256+threadIdx.x;
    if (idx >= M*Nld) return;
    int n = idx % Nld;
    float v = 0.f;
    if (n < Nvalid){
        for (int p=0;p<parts;p++) v += src[(size_t)p*pstride + idx];
        if (bias) v += bias[n];
    }
    dst[idx]=v;
}

// ================= scan kernels =================

__global__ void k_lstm0(const float* __restrict__ gx0, float* __restrict__ c,
                        f16* __restrict__ hhi, f16* __restrict__ hlo){
    int idx = blockIdx.x*256+threadIdx.x; if (idx>=B*H) return;
    int r=idx>>9, j=idx&511;
    float4 g = *(const float4*)&gx0[(size_t)r*G4H + (j<<2)];
    float cn = sigf(g.x)*tanhf(g.z);
    c[idx]=cn;
    float hv = sigf(g.w)*tanhf(cn);
    f16 h=(f16)hv; hhi[idx]=h; hlo[idx]=(f16)(hv-(float)h);
}

// fused: softmax/argmax + probs + attention + dur head + LSTM cell (next h hi/lo)
__global__ void k_postapply(const float* __restrict__ rawg, const float* __restrict__ S,
                       const f16* __restrict__ holdhi, const f16* __restrict__ holdlo,
                       const float* __restrict__ E, const float* __restrict__ wl,
                       const float* __restrict__ biascat,
                       const float* __restrict__ Wdur, const float* __restrict__ bdur,
                       float* __restrict__ outlab, float* __restrict__ outprobs,
                       float* __restrict__ outatt, float* __restrict__ outpad,
                       int* __restrict__ labs, float* __restrict__ wsdur,
                       float* __restrict__ c, f16* __restrict__ hNhi, f16* __restrict__ hNlo,
                       int tstep, int doLstm)
{
    int b=blockIdx.x, t=threadIdx.x;
    __shared__ float red[256];
    __shared__ float lg[C];
    __shared__ float sm2[2];
    __shared__ float aw[3];
    __shared__ int sbest;
    __shared__ float sdv;
    const float* zb = rawg + (size_t)b*NC;
    if (t<C) lg[t]=zb[G4H+t]+biascat[t];
    __syncthreads();
    if (t==0){
        float m=lg[0]; int best=0;
        for (int c2=1;c2<C;c2++) if (lg[c2]>m){m=lg[c2];best=c2;}
        float s=0.f; for (int c2=0;c2<C;c2++) s+=expf(lg[c2]-m);
        sm2[0]=m; sm2[1]=s; labs[b]=best; sbest=best;
        outlab[(size_t)tstep*B+b]=(float)best;
    }
    __syncthreads();
    if (t<C) outprobs[(size_t)b*(T*C)+tstep*C+t]=expf(lg[t]-sm2[0])/sm2[1];
    const float* S0 = S + (size_t)b*D;
    const float* S1 = S0 + (size_t)B*D;
    const float* S2 = S1 + (size_t)B*D;
    const float* q = zb + G4H + C;
    float pv[3]={0.f,0.f,0.f};
    for (int d=t; d<D; d+=256){ float qd=q[d]; pv[0]+=qd*S0[d]; pv[1]+=qd*S1[d]; pv[2]+=qd*S2[d]; }
    for (int k=0;k<3;k++){
        red[t]=pv[k]; __syncthreads();
        for (int s=128;s>0;s>>=1){ if (t<s) red[t]+=red[t+s]; __syncthreads(); }
        if (t==0) aw[k]=red[0];
        __syncthreads();
    }
    if (t==0){
        float m=fmaxf(aw[0],fmaxf(aw[1],aw[2]));
        float e0=expf(aw[0]-m), e1=expf(aw[1]-m), e2=expf(aw[2]-m);
        float s=e0+e1+e2;
        aw[0]=e0/s; aw[1]=e1/s; aw[2]=e2/s;
    }
    __syncthreads();
    float a0=aw[0],a1=aw[1],a2=aw[2];
    float dp=0.f;
    for (int d=t; d<D; d+=256){
        float av=a0*S0[d]+a1*S1[d]+a2*S2[d];
        outatt[(size_t)tstep*B*D + (size_t)b*D + d]=av;
        dp+=av*Wdur[d];
    }
    if (holdhi){
        for (int p=t;p<H;p+=256)
            dp += ((float)holdhi[(size_t)b*H+p] + (float)holdlo[(size_t)b*H+p])*Wdur[D+p];
    }
    red[t]=dp; __syncthreads();
    for (int s=128;s>0;s>>=1){ if (t<s) red[t]+=red[t+s]; __syncthreads(); }
    if (t==0){ float dv=red[0]+bdur[0]; outpad[(size_t)b*(T+1)+tstep+1]=dv; wsdur[b]=dv; sdv=dv; }
    __syncthreads();
    if (doLstm){
        int lb=sbest; float dv=sdv;
        for (int j=t;j<H;j+=256){
            float4 g4 = *(const float4*)&zb[4*j];
            float4 e4 = *(const float4*)&E[(size_t)lb*G4H+4*j];
            float4 w4 = *(const float4*)&wl[4*j];
            float gi=g4.x+e4.x+dv*w4.x;
            float gf=g4.y+e4.y+dv*w4.y;
            float gg=g4.z+e4.z+dv*w4.z;
            float go=g4.w+e4.w+dv*w4.w;
            size_t ci=(size_t)b*H+j;
            float cn = sigf(gf)*c[ci] + sigf(gi)*tanhf(gg);
            c[ci]=cn;
            float hv = sigf(go)*tanhf(cn);
            f16 hh=(f16)hv;
            hNhi[ci]=hh; hNlo[ci]=(f16)(hv-(float)hh);
        }
    }
}

// ================= host =================

extern "C" void kernel_launch(void* const* d_in, const int* in_sizes, int n_in,
                              void* d_out, int out_size, void* d_ws, size_t ws_size,
                              hipStream_t stream) {
    const float* S    = (const float*)d_in[0];
    const float* R    = (const float*)d_in[1];
    const float* clsW = (const float*)d_in[2];
    const float* clsb = (const float*)d_in[3];
    const float* durW = (const float*)d_in[4];
    const float* durb = (const float*)d_in[5];
    const float* linW = (const float*)d_in[6];
    const float* linb = (const float*)d_in[7];
    const float* Wih  = (const float*)d_in[8];
    const float* Whh  = (const float*)d_in[9];
    const float* bih  = (const float*)d_in[10];
    const float* bhh  = (const float*)d_in[11];
    const float* Wp   = (const float*)d_in[12];
    const float* bp   = (const float*)d_in[13];
    const float* Wdur = (const float*)d_in[14];
    const float* bdur = (const float*)d_in[15];
    const float* embed= (const float*)d_in[16];
    const float* Wattn= (const float*)d_in[17];

    float* out = (float*)d_out;
    float* outlab   = out;                 // [T,B]
    float* outprobs = out + 12800;         // [B,T,C]
    float* outca    = out + 627200;        // [B,C]
    float* outpad   = out + 651776;        // [B,T+1]
    float* outatt   = out + 665088;        // [T,B,D]

    float* ws = (float*)d_ws;
    // persistent block
    float* E       = ws + 0;               // 98,304
    float* wl      = ws + 98304;           // 2,048
    float* bias2p  = ws + 100352;          // 2,048
    float* biascat = ws + 102400;          // 64
    float* c       = ws + 102464;          // 262,144
    f16*   hAhi    = (f16*)(ws + 364608);  // 262,144 f16
    f16*   hAlo    = (f16*)(ws + 495680);
    f16*   hBhi    = (f16*)(ws + 626752);
    f16*   hBlo    = (f16*)(ws + 757824);
    float* wsdur   = ws + 888896;          // 512
    int*   labs    = (int*)(ws + 889408);  // 512
    f16*   Yhi     = (f16*)(ws + 889920);  // 512*144 f16
    f16*   Ylo     = (f16*)(ws + 926784);
    float* Y       = ws + 963648;          // 73,728
    float* x0p     = ws + 1037376;         // 512*1028
    f16*   x0hi    = (f16*)(ws + 1563712); // 512*1056 f16
    f16*   x0lo    = (f16*)(ws + 1834048);
    f16*   embhi   = (f16*)(ws + 2104384); // 48*1056 f16
    f16*   emblo   = (f16*)(ws + 2129728);
    // big scratch region, time-multiplexed:
    //  stage1 (x0): linWt hi/lo + x0part            [ends at float 10,066,496 ≈ 40.3 MB]
    //  stage2 (scan): Wcombt hi/lo + Wihp hi/lo + gx0p + rawg
    const size_t SB = 2155072;
    f16*   lwthi   = (f16*)(ws + SB);               // 1088*6304 f16
    f16*   lwtlo   = (f16*)(ws + SB + 3429376);
    float* x0part  = ws + SB + 6858752;             // 2*512*1028
    f16*   Wcthi   = (f16*)(ws + SB);               // 3136*512 f16
    f16*   Wctlo   = (f16*)(ws + SB + 802816);
    f16*   Wihphi  = (f16*)(ws + SB + 1605632);     // 2048*1056 f16
    f16*   Wihplo  = (f16*)(ws + SB + 2686976);
    float* gx0p    = ws + SB + 3768320;             // 512*2048
    float* rawg    = ws + SB + 4816896;             // 512*3120

    // ---- setup ----
    k_prep<<<8,256,0,stream>>>(bih,bhh,bp,Wih,bias2p,biascat,wl);
    k_cls<<<K*B,64,0,stream>>>(S,R,clsW,clsb,Y);
    k_curr_action<<<(B*C+255)/256,256,0,stream>>>(Y,outca);
    k_cvtY<<<(B*144+255)/256,256,0,stream>>>(Y,Yhi,Ylo);
    k_dur0<<<B,256,0,stream>>>(R,durW,durb,outpad);
    // linW -> transposed hi/lo [1088][6304]
    k_bt_build<<<dim3((FK+31)/32,(1088+31)/32),256,0,stream>>>(linW,lwthi,lwtlo,6288,1025,1025,1088,FK,1.f);
    // x0 = feat @ linW  (A gathered from Y/S/R, split-K 2)
    k_mfma<1><<<dim3(8,17,2),256,0,stream>>>(nullptr,nullptr,lwthi,lwtlo,x0part,nullptr,
                                             512,1028,FK,0,FK,1028,3168,(size_t)512*1028,
                                             Yhi,Ylo,S,R);
    k_red<<<(512*1028+255)/256,256,0,stream>>>(x0p,x0part,2,(size_t)512*1028,512,1028,DP1,linb);
    k_cvt<<<(512*KP+255)/256,256,0,stream>>>(x0p,x0hi,x0lo,512,1028,DP1,KP);
    // Wih^T (gate-perm rows) hi/lo  [overwrites dead linWt region]
    k_permrows<<<(G4H*KP+255)/256,256,0,stream>>>(Wih,Wihphi,Wihplo,DP1,KP,DP1);
    // gx0 = x0 @ WihT + bias2p
    k_mfma<0><<<dim3(8,32,1),256,0,stream>>>(x0hi,x0lo,Wihphi,Wihplo,gx0p,bias2p,
                                             512,G4H,KP,KP,KP,G4H,KP,0,
                                             nullptr,nullptr,nullptr,nullptr);
    k_cvt<<<(48*KP+255)/256,256,0,stream>>>(embed,embhi,emblo,48,1024,1024,KP);
    // E = embed @ WihT[0:1024] + bias2p
    k_mfma<0><<<dim3(1,32,1),256,0,stream>>>(embhi,emblo,Wihphi,Wihplo,E,bias2p,
                                             48,G4H,KP,KP,KP,G4H,KP,0,
                                             nullptr,nullptr,nullptr,nullptr);
    k_lstm0<<<(B*H+255)/256,256,0,stream>>>(gx0p,c,hAhi,hAlo);
    // Wcombt [3136][512]: rows 0..2047 Whh perm | 2048..2095 Wp^T | 2096..3119 Wattn^T/32 | pad 0
    k_permrows<<<(G4H*512+255)/256,256,0,stream>>>(Whh,Wcthi,Wctlo,H,H,H);
    k_bt_build<<<dim3(16,2),256,0,stream>>>(Wp,Wcthi+(size_t)2048*512,Wctlo+(size_t)2048*512,
                                            512,48,48,48,512,1.f);
    k_bt_build<<<dim3(16,32),256,0,stream>>>(Wattn,Wcthi+(size_t)2096*512,Wctlo+(size_t)2096*512,
                                             512,1024,1024,1024,512,0.03125f);
    k_zeroh<<<32,256,0,stream>>>(Wcthi+(size_t)3120*512,Wctlo+(size_t)3120*512,16*512);

    // ---- scan ----
    f16 *hCurHi=hAhi, *hCurLo=hAlo, *hPrvHi=hBhi, *hPrvLo=hBlo;
    for (int t=0;t<T;t++){
        k_mfma<0><<<dim3(8,49,1),256,0,stream>>>(hCurHi,hCurLo,Wcthi,Wctlo,rawg,nullptr,
                                                 512,NC,H,H,H,NC,H,0,
                                                 nullptr,nullptr,nullptr,nullptr);
        k_postapply<<<B,256,0,stream>>>(rawg,S,(t==0)?nullptr:hPrvHi,(t==0)?nullptr:hPrvLo,
                                        E,wl,biascat,Wdur,bdur,
                                        outlab,outprobs,outatt,outpad,labs,wsdur,
                                        c,hPrvHi,hPrvLo,t,(t<T-1)?1:0);
        f16* th=hPrvHi; hPrvHi=hCurHi; hCurHi=th;
        f16* tl=hPrvLo; hPrvLo=hCurLo; hCurLo=tl;
    }
}